// Round 5
// baseline (921.582 us; speedup 1.0000x reference)
//
#include <hip/hip_runtime.h>
#include <hip/hip_bf16.h>

#define N_NODES 10000
#define N_EDGES 160000
#define D_IN    128
#define D_EMB   512
#define D_HID   256

typedef unsigned short u16;
typedef __attribute__((ext_vector_type(8))) short short8;
typedef __attribute__((ext_vector_type(4))) float floatx4;

__device__ __forceinline__ float bf2f(u16 u) {
    union { unsigned int i; float f; } v; v.i = ((unsigned int)u) << 16; return v.f;
}
__device__ __forceinline__ u16 f2bf(float f) {
    union { float f; unsigned int i; } v; v.f = f;
    unsigned int x = v.i;
    return (u16)((x + 0x7fffu + ((x >> 16) & 1u)) >> 16);  // RNE
}
__device__ __forceinline__ float inval(const void* p, int fp32, int idx) {
    return fp32 ? ((const float*)p)[idx] : bf2f(((const u16*)p)[idx]);
}
// fast-math-immune badness tests (inf or NaN), bit-pattern based
__device__ __forceinline__ bool badf(float v) {
    unsigned int b = __float_as_uint(v);
    return (b & 0x7F800000u) == 0x7F800000u;
}
__device__ __forceinline__ bool badbf(u16 u) {
    return (u & 0x7F80u) == 0x7F80u;
}

// flag[0]: edge_index is int64-viewed-as-int32-pairs
// flag[1]: float tensors are fp32 (else bf16)
// flag[2]: inf/NaN in xl after layer-1 GEMM  -> canary 5.0
// flag[4]: inf/NaN in hh after GAT-3         -> canary 7.0
__device__ __forceinline__ int edge_src(const int* __restrict__ ei, int flg, int e) {
    int v = flg ? ei[2 * e] : ei[e];
    return min(max(v, 0), N_NODES - 1);
}
__device__ __forceinline__ int edge_dst(const int* __restrict__ ei, int flg, int e) {
    int v = flg ? ei[2 * N_EDGES + 2 * e] : ei[N_EDGES + e];
    return min(max(v, 0), N_NODES - 1);
}

// ---------------------------------------------------------------------------
__global__ void stage0_kernel(float* out, int n) {
    int i = blockIdx.x * 256 + threadIdx.x;
    if (i < n) out[i] = 9.0f;   // => pipeline started but softmax never wrote
}

__global__ void sentinel_kernel(float* out, int n) {
    int i = blockIdx.x * 256 + threadIdx.x;
    if (i < n) out[i] = 1.0f;   // => workspace too small
}

__global__ __launch_bounds__(256)
void detect_kernel(const int* __restrict__ ei, const u16* __restrict__ xu, int* flag) {
    __shared__ int s_or[256];
    __shared__ int s_cnt[256];
    int t = threadIdx.x;
    int v = 0;
    for (int k = t; k < 4096; k += 256) v |= ei[1 + 2 * k];
    int c = 0;
    for (int k = t; k < 4096; k += 256) {
        u16 u = xu[k];
        int ex = (u >> 7) & 0xFF;
        bool plaus = (u == 0) || (ex >= 64 && ex <= 191);
        if (!plaus) c++;
    }
    s_or[t] = v; s_cnt[t] = c;
    __syncthreads();
    for (int off = 128; off > 0; off >>= 1) {
        if (t < off) { s_or[t] |= s_or[t + off]; s_cnt[t] += s_cnt[t + off]; }
        __syncthreads();
    }
    if (t == 0) {
        flag[0] = (s_or[0] == 0) ? 1 : 0;
        flag[1] = (s_cnt[0] > 256) ? 1 : 0;
        flag[2] = 0; flag[3] = 0; flag[4] = 0;
    }
}

__global__ void badcheck_f32_kernel(const float* __restrict__ buf, int n, int* flag, int slot) {
    int i = blockIdx.x * 256 + threadIdx.x;
    bool bad = false;
    for (; i < n; i += gridDim.x * 256) if (badf(buf[i])) bad = true;
    if (bad) atomicOr(&flag[slot], 1);
}
__global__ void badcheck_bf16_kernel(const u16* __restrict__ buf, int n, int* flag, int slot) {
    int i = blockIdx.x * 256 + threadIdx.x;
    bool bad = false;
    for (; i < n; i += gridDim.x * 256) if (badbf(buf[i])) bad = true;
    if (bad) atomicOr(&flag[slot], 1);
}

// ---------------------------------------------------------------------------
// CSR build
// ---------------------------------------------------------------------------
__global__ void zero_counts_kernel(int* counts) {
    int i = blockIdx.x * 256 + threadIdx.x;
    if (i < N_NODES) counts[i] = 0;
}

__global__ void count_edges_kernel(const int* __restrict__ ei, const int* __restrict__ flag,
                                   int* counts) {
    int e = blockIdx.x * 256 + threadIdx.x;
    if (e < N_EDGES) atomicAdd(&counts[edge_dst(ei, flag[0], e)], 1);
}

__global__ __launch_bounds__(256)
void scan_counts_kernel(int* counts, int* rowptr) {
    __shared__ int part[256];
    int tid = threadIdx.x;
    const int CH = 40;
    int base = tid * CH;
    int loc[CH];
    int s = 0;
    #pragma unroll
    for (int i = 0; i < CH; i++) {
        int idx = base + i;
        int c = (idx < N_NODES) ? counts[idx] : 0;
        loc[i] = s; s += c;
    }
    part[tid] = s;
    __syncthreads();
    for (int off = 1; off < 256; off <<= 1) {
        int v = part[tid];
        int add = (tid >= off) ? part[tid - off] : 0;
        __syncthreads();
        part[tid] = v + add;
        __syncthreads();
    }
    int pre = (tid > 0) ? part[tid - 1] : 0;
    #pragma unroll
    for (int i = 0; i < CH; i++) {
        int idx = base + i;
        if (idx < N_NODES) { int v = pre + loc[i]; rowptr[idx] = v; counts[idx] = v; }
    }
    if (tid == 255) rowptr[N_NODES] = part[255];
}

__global__ void fill_esrcp_kernel(const int* __restrict__ ei, const int* __restrict__ flag,
                                  int* counts, int* esrcp) {
    int e = blockIdx.x * 256 + threadIdx.x;
    if (e < N_EDGES) {
        int flg = flag[0];
        int pos = atomicAdd(&counts[edge_dst(ei, flg, e)], 1);
        if (pos >= 0 && pos < N_EDGES) esrcp[pos] = edge_src(ei, flg, e);
    }
}

// ---------------------------------------------------------------------------
// bf16-split MFMA GEMM, C[M,N] = A[M,K] @ B[K,N]
// AMODE 0: A = raw float-tensor input (dtype per flag[1])
// AMODE 1: A = internal hi/lo bf16 pair (Ah,Al)
// MODE 0: store fp32 C. MODE 1: bias + leakyrelu(0.1) -> hi/lo bf16 pair.
// ---------------------------------------------------------------------------
template<int MODE, int AMODE>
__global__ __launch_bounds__(256)
void gemm_kernel(const void* __restrict__ Araw,
                 const u16* __restrict__ Ah, const u16* __restrict__ Al,
                 const void* __restrict__ Braw,
                 float* __restrict__ Cf, u16* __restrict__ Ch, u16* __restrict__ Cl,
                 const void* __restrict__ biasraw,
                 const int* __restrict__ flag,
                 int M, int N, int K)
{
    __shared__ u16 Ash[64 * 40];
    __shared__ u16 Asl[64 * 40];
    __shared__ u16 Bsh[64 * 40];
    __shared__ u16 Bsl[64 * 40];
    const int fp32 = flag[1];
    int tid  = threadIdx.x;
    int lane = tid & 63, wv = tid >> 6;
    int l15 = lane & 15, l4 = lane >> 4;
    int m0 = blockIdx.y * 64, n0 = blockIdx.x * 64;

    floatx4 acc[4];
    #pragma unroll
    for (int t = 0; t < 4; t++) acc[t] = (floatx4){0.f, 0.f, 0.f, 0.f};

    int arow = tid >> 2, akc = (tid & 3) * 8;
    int brow = tid >> 3, bnc = (tid & 7) * 8;

    const bool useAl = (AMODE == 1);
    for (int kk = 0; kk < K; kk += 32) {
        int gr = m0 + arow;
        if (AMODE == 1) {
            uint4 av  = {0u,0u,0u,0u}, avl = {0u,0u,0u,0u};
            if (gr < M) {
                av  = *(const uint4*)(Ah + (size_t)gr * K + kk + akc);
                avl = *(const uint4*)(Al + (size_t)gr * K + kk + akc);
            }
            *(uint4*)(&Ash[arow * 40 + akc]) = av;
            *(uint4*)(&Asl[arow * 40 + akc]) = avl;
        } else {
            if (fp32) {
                const float* Af = (const float*)Araw;
                float v[8] = {0,0,0,0,0,0,0,0};
                if (gr < M) {
                    float4 a0 = *(const float4*)(Af + (size_t)gr * K + kk + akc);
                    float4 a1 = *(const float4*)(Af + (size_t)gr * K + kk + akc + 4);
                    v[0]=a0.x; v[1]=a0.y; v[2]=a0.z; v[3]=a0.w;
                    v[4]=a1.x; v[5]=a1.y; v[6]=a1.z; v[7]=a1.w;
                }
                #pragma unroll
                for (int j = 0; j < 8; j++) {
                    u16 hi = f2bf(v[j]);
                    Ash[arow * 40 + akc + j] = hi;
                    Asl[arow * 40 + akc + j] = f2bf(v[j] - bf2f(hi));
                }
            } else {
                uint4 av = {0u,0u,0u,0u};
                if (gr < M) av = *(const uint4*)((const u16*)Araw + (size_t)gr * K + kk + akc);
                *(uint4*)(&Ash[arow * 40 + akc]) = av;
            }
        }
        if (fp32) {
            const float* Bf = (const float*)Braw;
            float4 b0 = *(const float4*)(Bf + (size_t)(kk + brow) * N + n0 + bnc);
            float4 b1 = *(const float4*)(Bf + (size_t)(kk + brow) * N + n0 + bnc + 4);
            float v[8] = {b0.x,b0.y,b0.z,b0.w,b1.x,b1.y,b1.z,b1.w};
            #pragma unroll
            for (int j = 0; j < 8; j++) {
                u16 hi = f2bf(v[j]);
                Bsh[(bnc + j) * 40 + brow] = hi;
                Bsl[(bnc + j) * 40 + brow] = f2bf(v[j] - bf2f(hi));
            }
        } else {
            union { uint4 v; u16 u[8]; } bb;
            bb.v = *(const uint4*)((const u16*)Braw + (size_t)(kk + brow) * N + n0 + bnc);
            #pragma unroll
            for (int j = 0; j < 8; j++) Bsh[(bnc + j) * 40 + brow] = bb.u[j];
        }
        __syncthreads();

        short8 afh = *(const short8*)(&Ash[(wv * 16 + l15) * 40 + l4 * 8]);
        short8 afl;
        if (useAl || fp32) afl = *(const short8*)(&Asl[(wv * 16 + l15) * 40 + l4 * 8]);
        #pragma unroll
        for (int t = 0; t < 4; t++) {
            short8 bfh = *(const short8*)(&Bsh[(t * 16 + l15) * 40 + l4 * 8]);
            acc[t] = __builtin_amdgcn_mfma_f32_16x16x32_bf16(afh, bfh, acc[t], 0, 0, 0);
            if (useAl || fp32)
                acc[t] = __builtin_amdgcn_mfma_f32_16x16x32_bf16(afl, bfh, acc[t], 0, 0, 0);
            if (fp32) {
                short8 bfl = *(const short8*)(&Bsl[(t * 16 + l15) * 40 + l4 * 8]);
                acc[t] = __builtin_amdgcn_mfma_f32_16x16x32_bf16(afh, bfl, acc[t], 0, 0, 0);
            }
        }
        __syncthreads();
    }

    #pragma unroll
    for (int t = 0; t < 4; t++) {
        int col = n0 + t * 16 + l15;
        #pragma unroll
        for (int r = 0; r < 4; r++) {
            int row = m0 + wv * 16 + l4 * 4 + r;
            if (row < M) {
                float v = acc[t][r];
                if (MODE == 0) {
                    Cf[(size_t)row * N + col] = v;
                } else {
                    v += inval(biasraw, fp32, col);
                    v = v > 0.f ? v : 0.1f * v;
                    u16 hi = f2bf(v);
                    Ch[(size_t)row * N + col] = hi;
                    Cl[(size_t)row * N + col] = f2bf(v - bf2f(hi));
                }
            }
        }
    }
}

// ---------------------------------------------------------------------------
// Fused GATv2 edge kernel
// ---------------------------------------------------------------------------
#define MAXD 512
__global__ __launch_bounds__(256)
void gat_edge_kernel(const int* __restrict__ rowptr, const int* __restrict__ esrcp,
                     const float* __restrict__ xl, const float* __restrict__ xr,
                     const void* __restrict__ att, const void* __restrict__ bias,
                     const int* __restrict__ flag,
                     u16* __restrict__ hh, u16* __restrict__ hl)
{
    __shared__ float s_xr[D_EMB];
    __shared__ float s_att[D_EMB];
    __shared__ float s_e[MAXD];
    __shared__ int   s_src[MAXD];
    __shared__ float s_inv;
    int n = blockIdx.x;
    int tid = threadIdx.x, lane = tid & 63, wv = tid >> 6;
    int fp32 = flag[1];
    int beg = rowptr[n];
    int deg = rowptr[n + 1] - beg;
    if (deg > MAXD) deg = MAXD;
    if (deg < 0) deg = 0;

    for (int d = tid; d < D_EMB; d += 256) {
        s_xr[d]  = xr[(size_t)n * D_EMB + d];
        s_att[d] = inval(att, fp32, d);
    }
    __syncthreads();

    for (int j = wv; j < deg; j += 4) {
        int s = esrcp[beg + j];
        const float4* xls = (const float4*)(xl + (size_t)s * D_EMB);
        int d0 = lane * 8;
        float4 v0 = xls[lane * 2];
        float4 v1 = xls[lane * 2 + 1];
        float a = 0.f, t;
        t = v0.x + s_xr[d0 + 0]; a += s_att[d0 + 0] * (t > 0.f ? t : 0.2f * t);
        t = v0.y + s_xr[d0 + 1]; a += s_att[d0 + 1] * (t > 0.f ? t : 0.2f * t);
        t = v0.z + s_xr[d0 + 2]; a += s_att[d0 + 2] * (t > 0.f ? t : 0.2f * t);
        t = v0.w + s_xr[d0 + 3]; a += s_att[d0 + 3] * (t > 0.f ? t : 0.2f * t);
        t = v1.x + s_xr[d0 + 4]; a += s_att[d0 + 4] * (t > 0.f ? t : 0.2f * t);
        t = v1.y + s_xr[d0 + 5]; a += s_att[d0 + 5] * (t > 0.f ? t : 0.2f * t);
        t = v1.z + s_xr[d0 + 6]; a += s_att[d0 + 6] * (t > 0.f ? t : 0.2f * t);
        t = v1.w + s_xr[d0 + 7]; a += s_att[d0 + 7] * (t > 0.f ? t : 0.2f * t);
        #pragma unroll
        for (int o = 32; o > 0; o >>= 1) a += __shfl_down(a, o);
        if (lane == 0) { s_e[j] = a; s_src[j] = s; }
    }
    __syncthreads();

    if (wv == 0) {
        float m = -3.4e38f;
        for (int j = lane; j < deg; j += 64) m = fmaxf(m, s_e[j]);
        #pragma unroll
        for (int o = 32; o > 0; o >>= 1) m = fmaxf(m, __shfl_down(m, o));
        m = __shfl(m, 0);
        float sum = 0.f;
        for (int j = lane; j < deg; j += 64) {
            float w = __expf(s_e[j] - m);
            s_e[j] = w;
            sum += w;
        }
        #pragma unroll
        for (int o = 32; o > 0; o >>= 1) sum += __shfl_down(sum, o);
        if (lane == 0) s_inv = 1.f / (sum + 1e-16f);
    }
    __syncthreads();

    float inv = s_inv;
    float a0 = 0.f, a1 = 0.f;
    for (int j = 0; j < deg; j++) {
        float w = s_e[j];
        const float* xs = xl + (size_t)s_src[j] * D_EMB;
        a0 += w * xs[tid];
        a1 += w * xs[tid + 256];
    }
    a0 = tanhf(a0 * inv + inval(bias, fp32, tid));
    a1 = tanhf(a1 * inv + inval(bias, fp32, tid + 256));
    u16 h0 = f2bf(a0), h1 = f2bf(a1);
    hh[(size_t)n * D_EMB + tid]       = h0;
    hh[(size_t)n * D_EMB + tid + 256] = h1;
    hl[(size_t)n * D_EMB + tid]       = f2bf(a0 - bf2f(h0));
    hl[(size_t)n * D_EMB + tid + 256] = f2bf(a1 - bf2f(h1));
}

// ---------------------------------------------------------------------------
__global__ __launch_bounds__(256)
void logit_kernel(const u16* __restrict__ m2h, const u16* __restrict__ m2l,
                  const void* __restrict__ A3, const void* __restrict__ c3,
                  const int* __restrict__ flag,
                  float* __restrict__ logits)
{
    int tid = threadIdx.x, lane = tid & 63, wv = tid >> 6;
    int node = blockIdx.x * 4 + wv;
    if (node >= N_NODES) return;
    int fp32 = flag[1];
    const u16* rh = m2h + (size_t)node * D_HID;
    const u16* rl = m2l + (size_t)node * D_HID;
    int d0 = lane * 4;
    float a = 0.f;
    #pragma unroll
    for (int j = 0; j < 4; j++) {
        float hv = bf2f(rh[d0 + j]) + bf2f(rl[d0 + j]);
        a += hv * inval(A3, fp32, d0 + j);
    }
    #pragma unroll
    for (int o = 32; o > 0; o >>= 1) a += __shfl_down(a, o);
    if (lane == 0) logits[node] = a + inval(c3, fp32, 0);
}

// ---------------------------------------------------------------------------
// Softmax over all nodes -> FLOAT32 output (the R0-R4 bug: output is f32!)
// ---------------------------------------------------------------------------
__global__ __launch_bounds__(256)
void softmax_kernel(const float* __restrict__ logits, const int* __restrict__ flag,
                    float* __restrict__ out)
{
    __shared__ float red[4];
    __shared__ float s_m, s_s;
    __shared__ int s_bad;
    int tid = threadIdx.x, lane = tid & 63, wv = tid >> 6;
    if (tid == 0) s_bad = 0;
    __syncthreads();
    bool bad = false;
    for (int i = tid; i < N_NODES; i += 256) if (badf(logits[i])) bad = true;
    if (bad) s_bad = 1;   // benign race: all writers store 1
    __syncthreads();
    int f2 = flag[2], f4 = flag[4], sb = s_bad;
    if (f2 || f4 || sb) {
        float v = f2 ? 5.0f : (f4 ? 7.0f : 3.0f);
        for (int i = tid; i < N_NODES; i += 256) out[i] = v;
        return;
    }
    float m = -3.4e38f;
    for (int i = tid; i < N_NODES; i += 256) m = fmaxf(m, logits[i]);
    #pragma unroll
    for (int o = 32; o > 0; o >>= 1) m = fmaxf(m, __shfl_down(m, o));
    if (lane == 0) red[wv] = m;
    __syncthreads();
    if (tid == 0) {
        float mm = red[0];
        for (int i = 1; i < 4; i++) mm = fmaxf(mm, red[i]);
        s_m = mm;
    }
    __syncthreads();
    float mm = s_m;
    float s = 0.f;
    for (int i = tid; i < N_NODES; i += 256) s += __expf(logits[i] - mm);
    #pragma unroll
    for (int o = 32; o > 0; o >>= 1) s += __shfl_down(s, o);
    if (lane == 0) red[wv] = s;
    __syncthreads();
    if (tid == 0) {
        float ss = 0.f;
        for (int i = 0; i < 4; i++) ss += red[i];
        s_s = ss;
    }
    __syncthreads();
    float invs = 1.f / s_s;
    for (int i = tid; i < N_NODES; i += 256) out[i] = __expf(logits[i] - mm) * invs;
}

// ---------------------------------------------------------------------------
extern "C" void kernel_launch(void* const* d_in, const int* in_sizes, int n_in,
                              void* d_out, int out_size, void* d_ws, size_t ws_size,
                              hipStream_t stream)
{
    const void* x   = d_in[0];
    const int*  ei  = (const int*)d_in[1];
    const void* Wl[3]  = {d_in[2],  d_in[6],  d_in[10]};
    const void* Wr[3]  = {d_in[3],  d_in[7],  d_in[11]};
    const void* att[3] = {d_in[4],  d_in[8],  d_in[12]};
    const void* bia[3] = {d_in[5],  d_in[9],  d_in[13]};
    const void* A1 = d_in[14];
    const void* c1 = d_in[15];
    const void* A2 = d_in[16];
    const void* c2 = d_in[17];
    const void* A3 = d_in[18];
    const void* c3 = d_in[19];

    char* p = (char*)d_ws;
    auto alloc = [&](size_t bytes) {
        char* r = p;
        p += (bytes + 255) & ~(size_t)255;
        return r;
    };
    float* xl     = (float*)alloc((size_t)N_NODES * D_EMB * 4);
    float* xr     = (float*)alloc((size_t)N_NODES * D_EMB * 4);
    u16*   hh     = (u16*)  alloc((size_t)N_NODES * D_EMB * 2);
    u16*   hl     = (u16*)  alloc((size_t)N_NODES * D_EMB * 2);
    int*   esrcp  = (int*)  alloc((size_t)N_EDGES * 4);
    int*   rowptr = (int*)  alloc((size_t)(N_NODES + 1) * 4);
    int*   counts = (int*)  alloc((size_t)N_NODES * 4);
    int*   flag   = (int*)  alloc(256);
    size_t needed = (size_t)(p - (char*)d_ws);

    if (ws_size < needed) {
        sentinel_kernel<<<(out_size + 255) / 256, 256, 0, stream>>>((float*)d_out, out_size);
        return;
    }

    u16*   m1h    = (u16*)xl;
    u16*   m1l    = (u16*)((char*)xl + 5120000);
    u16*   m2h    = (u16*)((char*)xl + 10240000);
    u16*   m2l    = (u16*)((char*)xl + 15360000);
    float* logits = (float*)xr;

    // probe: paint output 9.0; softmax must overwrite it
    stage0_kernel<<<(out_size + 255) / 256, 256, 0, stream>>>((float*)d_out, out_size);

    detect_kernel<<<1, 256, 0, stream>>>(ei, (const u16*)x, flag);
    zero_counts_kernel<<<(N_NODES + 255) / 256, 256, 0, stream>>>(counts);
    count_edges_kernel<<<(N_EDGES + 255) / 256, 256, 0, stream>>>(ei, flag, counts);
    scan_counts_kernel<<<1, 256, 0, stream>>>(counts, rowptr);
    fill_esrcp_kernel<<<(N_EDGES + 255) / 256, 256, 0, stream>>>(ei, flag, counts, esrcp);

    dim3 g512(D_EMB / 64, (N_NODES + 63) / 64);
    dim3 g256(D_HID / 64, (N_NODES + 63) / 64);

    gemm_kernel<0, 0><<<g512, 256, 0, stream>>>(x, nullptr, nullptr, Wl[0], xl, nullptr, nullptr, nullptr, flag, N_NODES, D_EMB, D_IN);
    gemm_kernel<0, 0><<<g512, 256, 0, stream>>>(x, nullptr, nullptr, Wr[0], xr, nullptr, nullptr, nullptr, flag, N_NODES, D_EMB, D_IN);
    badcheck_f32_kernel<<<64, 256, 0, stream>>>(xl, N_NODES * D_EMB, flag, 2);
    gat_edge_kernel<<<N_NODES, 256, 0, stream>>>(rowptr, esrcp, xl, xr, att[0], bia[0], flag, hh, hl);

    for (int L = 1; L < 3; L++) {
        gemm_kernel<0, 1><<<g512, 256, 0, stream>>>(nullptr, hh, hl, Wl[L], xl, nullptr, nullptr, nullptr, flag, N_NODES, D_EMB, D_EMB);
        gemm_kernel<0, 1><<<g512, 256, 0, stream>>>(nullptr, hh, hl, Wr[L], xr, nullptr, nullptr, nullptr, flag, N_NODES, D_EMB, D_EMB);
        gat_edge_kernel<<<N_NODES, 256, 0, stream>>>(rowptr, esrcp, xl, xr, att[L], bia[L], flag, hh, hl);
    }
    badcheck_bf16_kernel<<<64, 256, 0, stream>>>(hh, N_NODES * D_EMB, flag, 4);

    gemm_kernel<1, 1><<<g256, 256, 0, stream>>>(nullptr, hh, hl, A1, nullptr, m1h, m1l, c1, flag, N_NODES, D_HID, D_EMB);
    gemm_kernel<1, 1><<<g256, 256, 0, stream>>>(nullptr, m1h, m1l, A2, nullptr, m2h, m2l, c2, flag, N_NODES, D_HID, D_HID);
    logit_kernel<<<(N_NODES + 3) / 4, 256, 0, stream>>>(m2h, m2l, A3, c3, flag, logits);
    softmax_kernel<<<1, 256, 0, stream>>>(logits, flag, (float*)d_out);
}

// Round 6
// 752.324 us; speedup vs baseline: 1.2250x; 1.2250x over previous
//
#include <hip/hip_runtime.h>
#include <hip/hip_bf16.h>

#define N_NODES 10000
#define N_EDGES 160000
#define D_IN    128
#define D_EMB   512
#define D_HID   256

typedef unsigned short u16;
typedef __attribute__((ext_vector_type(8))) short short8;
typedef __attribute__((ext_vector_type(4))) float floatx4;

__device__ __forceinline__ float bf2f(u16 u) {
    union { unsigned int i; float f; } v; v.i = ((unsigned int)u) << 16; return v.f;
}
__device__ __forceinline__ u16 f2bf(float f) {
    union { float f; unsigned int i; } v; v.f = f;
    unsigned int x = v.i;
    return (u16)((x + 0x7fffu + ((x >> 16) & 1u)) >> 16);  // RNE
}
__device__ __forceinline__ float inval(const void* p, int fp32, int idx) {
    return fp32 ? ((const float*)p)[idx] : bf2f(((const u16*)p)[idx]);
}

// flag[0]: edge_index is int64-viewed-as-int32-pairs
// flag[1]: float tensors are fp32 (else bf16)
__device__ __forceinline__ int edge_src(const int* __restrict__ ei, int flg, int e) {
    int v = flg ? ei[2 * e] : ei[e];
    return min(max(v, 0), N_NODES - 1);
}
__device__ __forceinline__ int edge_dst(const int* __restrict__ ei, int flg, int e) {
    int v = flg ? ei[2 * N_EDGES + 2 * e] : ei[N_EDGES + e];
    return min(max(v, 0), N_NODES - 1);
}

// ---------------------------------------------------------------------------
__global__ void sentinel_kernel(float* out, int n) {
    int i = blockIdx.x * 256 + threadIdx.x;
    if (i < n) out[i] = 1.0f;   // => workspace too small
}

__global__ __launch_bounds__(256)
void detect_kernel(const int* __restrict__ ei, const u16* __restrict__ xu, int* flag) {
    __shared__ int s_or[256];
    __shared__ int s_cnt[256];
    int t = threadIdx.x;
    int v = 0;
    for (int k = t; k < 4096; k += 256) v |= ei[1 + 2 * k];
    int c = 0;
    for (int k = t; k < 4096; k += 256) {
        u16 u = xu[k];
        int ex = (u >> 7) & 0xFF;
        bool plaus = (u == 0) || (ex >= 64 && ex <= 191);
        if (!plaus) c++;
    }
    s_or[t] = v; s_cnt[t] = c;
    __syncthreads();
    for (int off = 128; off > 0; off >>= 1) {
        if (t < off) { s_or[t] |= s_or[t + off]; s_cnt[t] += s_cnt[t + off]; }
        __syncthreads();
    }
    if (t == 0) {
        flag[0] = (s_or[0] == 0) ? 1 : 0;
        flag[1] = (s_cnt[0] > 256) ? 1 : 0;
    }
}

// ---------------------------------------------------------------------------
// CSR build
// ---------------------------------------------------------------------------
__global__ void zero_counts_kernel(int* counts) {
    int i = blockIdx.x * 256 + threadIdx.x;
    if (i < N_NODES) counts[i] = 0;
}

__global__ void count_edges_kernel(const int* __restrict__ ei, const int* __restrict__ flag,
                                   int* counts) {
    int e = blockIdx.x * 256 + threadIdx.x;
    if (e < N_EDGES) atomicAdd(&counts[edge_dst(ei, flag[0], e)], 1);
}

__global__ __launch_bounds__(256)
void scan_counts_kernel(int* counts, int* rowptr) {
    __shared__ int part[256];
    int tid = threadIdx.x;
    const int CH = 40;
    int base = tid * CH;
    int loc[CH];
    int s = 0;
    #pragma unroll
    for (int i = 0; i < CH; i++) {
        int idx = base + i;
        int c = (idx < N_NODES) ? counts[idx] : 0;
        loc[i] = s; s += c;
    }
    part[tid] = s;
    __syncthreads();
    for (int off = 1; off < 256; off <<= 1) {
        int v = part[tid];
        int add = (tid >= off) ? part[tid - off] : 0;
        __syncthreads();
        part[tid] = v + add;
        __syncthreads();
    }
    int pre = (tid > 0) ? part[tid - 1] : 0;
    #pragma unroll
    for (int i = 0; i < CH; i++) {
        int idx = base + i;
        if (idx < N_NODES) { int v = pre + loc[i]; rowptr[idx] = v; counts[idx] = v; }
    }
    if (tid == 255) rowptr[N_NODES] = part[255];
}

__global__ void fill_esrcp_kernel(const int* __restrict__ ei, const int* __restrict__ flag,
                                  int* counts, int* esrcp) {
    int e = blockIdx.x * 256 + threadIdx.x;
    if (e < N_EDGES) {
        int flg = flag[0];
        int pos = atomicAdd(&counts[edge_dst(ei, flg, e)], 1);
        if (pos >= 0 && pos < N_EDGES) esrcp[pos] = edge_src(ei, flg, e);
    }
}

// ---------------------------------------------------------------------------
// bf16-split MFMA GEMM, C[M,N] = A[M,K] @ B[K,N]
// AMODE 0: A = raw float-tensor input (dtype per flag[1])
// AMODE 1: A = internal hi/lo bf16 pair (Ah,Al)
// MODE 0: store fp32 C. MODE 1: bias + leakyrelu(0.1) -> hi/lo bf16 pair.
// ---------------------------------------------------------------------------
template<int MODE, int AMODE>
__global__ __launch_bounds__(256)
void gemm_kernel(const void* __restrict__ Araw,
                 const u16* __restrict__ Ah, const u16* __restrict__ Al,
                 const void* __restrict__ Braw,
                 float* __restrict__ Cf, u16* __restrict__ Ch, u16* __restrict__ Cl,
                 const void* __restrict__ biasraw,
                 const int* __restrict__ flag,
                 int M, int N, int K)
{
    __shared__ u16 Ash[64 * 40];
    __shared__ u16 Asl[64 * 40];
    __shared__ u16 Bsh[64 * 40];
    __shared__ u16 Bsl[64 * 40];
    const int fp32 = flag[1];
    int tid  = threadIdx.x;
    int lane = tid & 63, wv = tid >> 6;
    int l15 = lane & 15, l4 = lane >> 4;
    int m0 = blockIdx.y * 64, n0 = blockIdx.x * 64;

    floatx4 acc[4];
    #pragma unroll
    for (int t = 0; t < 4; t++) acc[t] = (floatx4){0.f, 0.f, 0.f, 0.f};

    int arow = tid >> 2, akc = (tid & 3) * 8;
    int brow = tid >> 3, bnc = (tid & 7) * 8;

    const bool useAl = (AMODE == 1);
    for (int kk = 0; kk < K; kk += 32) {
        int gr = m0 + arow;
        if (AMODE == 1) {
            uint4 av  = {0u,0u,0u,0u}, avl = {0u,0u,0u,0u};
            if (gr < M) {
                av  = *(const uint4*)(Ah + (size_t)gr * K + kk + akc);
                avl = *(const uint4*)(Al + (size_t)gr * K + kk + akc);
            }
            *(uint4*)(&Ash[arow * 40 + akc]) = av;
            *(uint4*)(&Asl[arow * 40 + akc]) = avl;
        } else {
            if (fp32) {
                const float* Af = (const float*)Araw;
                float v[8] = {0,0,0,0,0,0,0,0};
                if (gr < M) {
                    float4 a0 = *(const float4*)(Af + (size_t)gr * K + kk + akc);
                    float4 a1 = *(const float4*)(Af + (size_t)gr * K + kk + akc + 4);
                    v[0]=a0.x; v[1]=a0.y; v[2]=a0.z; v[3]=a0.w;
                    v[4]=a1.x; v[5]=a1.y; v[6]=a1.z; v[7]=a1.w;
                }
                #pragma unroll
                for (int j = 0; j < 8; j++) {
                    u16 hi = f2bf(v[j]);
                    Ash[arow * 40 + akc + j] = hi;
                    Asl[arow * 40 + akc + j] = f2bf(v[j] - bf2f(hi));
                }
            } else {
                uint4 av = {0u,0u,0u,0u};
                if (gr < M) av = *(const uint4*)((const u16*)Araw + (size_t)gr * K + kk + akc);
                *(uint4*)(&Ash[arow * 40 + akc]) = av;
            }
        }
        if (fp32) {
            const float* Bf = (const float*)Braw;
            float4 b0 = *(const float4*)(Bf + (size_t)(kk + brow) * N + n0 + bnc);
            float4 b1 = *(const float4*)(Bf + (size_t)(kk + brow) * N + n0 + bnc + 4);
            float v[8] = {b0.x,b0.y,b0.z,b0.w,b1.x,b1.y,b1.z,b1.w};
            #pragma unroll
            for (int j = 0; j < 8; j++) {
                u16 hi = f2bf(v[j]);
                Bsh[(bnc + j) * 40 + brow] = hi;
                Bsl[(bnc + j) * 40 + brow] = f2bf(v[j] - bf2f(hi));
            }
        } else {
            union { uint4 v; u16 u[8]; } bb;
            bb.v = *(const uint4*)((const u16*)Braw + (size_t)(kk + brow) * N + n0 + bnc);
            #pragma unroll
            for (int j = 0; j < 8; j++) Bsh[(bnc + j) * 40 + brow] = bb.u[j];
        }
        __syncthreads();

        short8 afh = *(const short8*)(&Ash[(wv * 16 + l15) * 40 + l4 * 8]);
        short8 afl;
        if (useAl || fp32) afl = *(const short8*)(&Asl[(wv * 16 + l15) * 40 + l4 * 8]);
        #pragma unroll
        for (int t = 0; t < 4; t++) {
            short8 bfh = *(const short8*)(&Bsh[(t * 16 + l15) * 40 + l4 * 8]);
            acc[t] = __builtin_amdgcn_mfma_f32_16x16x32_bf16(afh, bfh, acc[t], 0, 0, 0);
            if (useAl || fp32)
                acc[t] = __builtin_amdgcn_mfma_f32_16x16x32_bf16(afl, bfh, acc[t], 0, 0, 0);
            if (fp32) {
                short8 bfl = *(const short8*)(&Bsl[(t * 16 + l15) * 40 + l4 * 8]);
                acc[t] = __builtin_amdgcn_mfma_f32_16x16x32_bf16(afh, bfl, acc[t], 0, 0, 0);
            }
        }
        __syncthreads();
    }

    #pragma unroll
    for (int t = 0; t < 4; t++) {
        int col = n0 + t * 16 + l15;
        #pragma unroll
        for (int r = 0; r < 4; r++) {
            int row = m0 + wv * 16 + l4 * 4 + r;
            if (row < M) {
                float v = acc[t][r];
                if (MODE == 0) {
                    Cf[(size_t)row * N + col] = v;
                } else {
                    v += inval(biasraw, fp32, col);
                    v = v > 0.f ? v : 0.1f * v;
                    u16 hi = f2bf(v);
                    Ch[(size_t)row * N + col] = hi;
                    Cl[(size_t)row * N + col] = f2bf(v - bf2f(hi));
                }
            }
        }
    }
}

// ---------------------------------------------------------------------------
// Fused GATv2 edge kernel
// ---------------------------------------------------------------------------
#define MAXD 512
__global__ __launch_bounds__(256)
void gat_edge_kernel(const int* __restrict__ rowptr, const int* __restrict__ esrcp,
                     const float* __restrict__ xl, const float* __restrict__ xr,
                     const void* __restrict__ att, const void* __restrict__ bias,
                     const int* __restrict__ flag,
                     u16* __restrict__ hh, u16* __restrict__ hl)
{
    __shared__ float s_xr[D_EMB];
    __shared__ float s_att[D_EMB];
    __shared__ float s_e[MAXD];
    __shared__ int   s_src[MAXD];
    __shared__ float s_inv;
    int n = blockIdx.x;
    int tid = threadIdx.x, lane = tid & 63, wv = tid >> 6;
    int fp32 = flag[1];
    int beg = rowptr[n];
    int deg = rowptr[n + 1] - beg;
    if (deg > MAXD) deg = MAXD;
    if (deg < 0) deg = 0;

    for (int d = tid; d < D_EMB; d += 256) {
        s_xr[d]  = xr[(size_t)n * D_EMB + d];
        s_att[d] = inval(att, fp32, d);
    }
    __syncthreads();

    for (int j = wv; j < deg; j += 4) {
        int s = esrcp[beg + j];
        const float4* xls = (const float4*)(xl + (size_t)s * D_EMB);
        int d0 = lane * 8;
        float4 v0 = xls[lane * 2];
        float4 v1 = xls[lane * 2 + 1];
        float a = 0.f, t;
        t = v0.x + s_xr[d0 + 0]; a += s_att[d0 + 0] * (t > 0.f ? t : 0.2f * t);
        t = v0.y + s_xr[d0 + 1]; a += s_att[d0 + 1] * (t > 0.f ? t : 0.2f * t);
        t = v0.z + s_xr[d0 + 2]; a += s_att[d0 + 2] * (t > 0.f ? t : 0.2f * t);
        t = v0.w + s_xr[d0 + 3]; a += s_att[d0 + 3] * (t > 0.f ? t : 0.2f * t);
        t = v1.x + s_xr[d0 + 4]; a += s_att[d0 + 4] * (t > 0.f ? t : 0.2f * t);
        t = v1.y + s_xr[d0 + 5]; a += s_att[d0 + 5] * (t > 0.f ? t : 0.2f * t);
        t = v1.z + s_xr[d0 + 6]; a += s_att[d0 + 6] * (t > 0.f ? t : 0.2f * t);
        t = v1.w + s_xr[d0 + 7]; a += s_att[d0 + 7] * (t > 0.f ? t : 0.2f * t);
        #pragma unroll
        for (int o = 32; o > 0; o >>= 1) a += __shfl_down(a, o);
        if (lane == 0) { s_e[j] = a; s_src[j] = s; }
    }
    __syncthreads();

    if (wv == 0) {
        float m = -3.4e38f;
        for (int j = lane; j < deg; j += 64) m = fmaxf(m, s_e[j]);
        #pragma unroll
        for (int o = 32; o > 0; o >>= 1) m = fmaxf(m, __shfl_down(m, o));
        m = __shfl(m, 0);
        float sum = 0.f;
        for (int j = lane; j < deg; j += 64) {
            float w = __expf(s_e[j] - m);
            s_e[j] = w;
            sum += w;
        }
        #pragma unroll
        for (int o = 32; o > 0; o >>= 1) sum += __shfl_down(sum, o);
        if (lane == 0) s_inv = 1.f / (sum + 1e-16f);
    }
    __syncthreads();

    float inv = s_inv;
    float a0 = 0.f, a1 = 0.f;
    for (int j = 0; j < deg; j++) {
        float w = s_e[j];
        const float* xs = xl + (size_t)s_src[j] * D_EMB;
        a0 += w * xs[tid];
        a1 += w * xs[tid + 256];
    }
    a0 = tanhf(a0 * inv + inval(bias, fp32, tid));
    a1 = tanhf(a1 * inv + inval(bias, fp32, tid + 256));
    u16 h0 = f2bf(a0), h1 = f2bf(a1);
    hh[(size_t)n * D_EMB + tid]       = h0;
    hh[(size_t)n * D_EMB + tid + 256] = h1;
    hl[(size_t)n * D_EMB + tid]       = f2bf(a0 - bf2f(h0));
    hl[(size_t)n * D_EMB + tid + 256] = f2bf(a1 - bf2f(h1));
}

// ---------------------------------------------------------------------------
__global__ __launch_bounds__(256)
void logit_kernel(const u16* __restrict__ m2h, const u16* __restrict__ m2l,
                  const void* __restrict__ A3, const void* __restrict__ c3,
                  const int* __restrict__ flag,
                  float* __restrict__ logits)
{
    int tid = threadIdx.x, lane = tid & 63, wv = tid >> 6;
    int node = blockIdx.x * 4 + wv;
    if (node >= N_NODES) return;
    int fp32 = flag[1];
    const u16* rh = m2h + (size_t)node * D_HID;
    const u16* rl = m2l + (size_t)node * D_HID;
    int d0 = lane * 4;
    float a = 0.f;
    #pragma unroll
    for (int j = 0; j < 4; j++) {
        float hv = bf2f(rh[d0 + j]) + bf2f(rl[d0 + j]);
        a += hv * inval(A3, fp32, d0 + j);
    }
    #pragma unroll
    for (int o = 32; o > 0; o >>= 1) a += __shfl_down(a, o);
    if (lane == 0) logits[node] = a + inval(c3, fp32, 0);
}

// ---------------------------------------------------------------------------
// Softmax over all nodes -> float32 output
// ---------------------------------------------------------------------------
__global__ __launch_bounds__(256)
void softmax_kernel(const float* __restrict__ logits, float* __restrict__ out)
{
    __shared__ float red[4];
    __shared__ float s_m, s_s;
    int tid = threadIdx.x, lane = tid & 63, wv = tid >> 6;
    float m = -3.4e38f;
    for (int i = tid; i < N_NODES; i += 256) m = fmaxf(m, logits[i]);
    #pragma unroll
    for (int o = 32; o > 0; o >>= 1) m = fmaxf(m, __shfl_down(m, o));
    if (lane == 0) red[wv] = m;
    __syncthreads();
    if (tid == 0) {
        float mm = red[0];
        for (int i = 1; i < 4; i++) mm = fmaxf(mm, red[i]);
        s_m = mm;
    }
    __syncthreads();
    float mm = s_m;
    float s = 0.f;
    for (int i = tid; i < N_NODES; i += 256) s += __expf(logits[i] - mm);
    #pragma unroll
    for (int o = 32; o > 0; o >>= 1) s += __shfl_down(s, o);
    if (lane == 0) red[wv] = s;
    __syncthreads();
    if (tid == 0) {
        float ss = 0.f;
        for (int i = 0; i < 4; i++) ss += red[i];
        s_s = ss;
    }
    __syncthreads();
    float invs = 1.f / s_s;
    for (int i = tid; i < N_NODES; i += 256) out[i] = __expf(logits[i] - mm) * invs;
}

// ---------------------------------------------------------------------------
extern "C" void kernel_launch(void* const* d_in, const int* in_sizes, int n_in,
                              void* d_out, int out_size, void* d_ws, size_t ws_size,
                              hipStream_t stream)
{
    const void* x   = d_in[0];
    const int*  ei  = (const int*)d_in[1];
    const void* Wl[3]  = {d_in[2],  d_in[6],  d_in[10]};
    const void* Wr[3]  = {d_in[3],  d_in[7],  d_in[11]};
    const void* att[3] = {d_in[4],  d_in[8],  d_in[12]};
    const void* bia[3] = {d_in[5],  d_in[9],  d_in[13]};
    const void* A1 = d_in[14];
    const void* c1 = d_in[15];
    const void* A2 = d_in[16];
    const void* c2 = d_in[17];
    const void* A3 = d_in[18];
    const void* c3 = d_in[19];

    char* p = (char*)d_ws;
    auto alloc = [&](size_t bytes) {
        char* r = p;
        p += (bytes + 255) & ~(size_t)255;
        return r;
    };
    float* xl     = (float*)alloc((size_t)N_NODES * D_EMB * 4);
    float* xr     = (float*)alloc((size_t)N_NODES * D_EMB * 4);
    u16*   hh     = (u16*)  alloc((size_t)N_NODES * D_EMB * 2);
    u16*   hl     = (u16*)  alloc((size_t)N_NODES * D_EMB * 2);
    int*   esrcp  = (int*)  alloc((size_t)N_EDGES * 4);
    int*   rowptr = (int*)  alloc((size_t)(N_NODES + 1) * 4);
    int*   counts = (int*)  alloc((size_t)N_NODES * 4);
    int*   flag   = (int*)  alloc(256);
    size_t needed = (size_t)(p - (char*)d_ws);

    if (ws_size < needed) {
        sentinel_kernel<<<(out_size + 255) / 256, 256, 0, stream>>>((float*)d_out, out_size);
        return;
    }

    u16*   m1h    = (u16*)xl;
    u16*   m1l    = (u16*)((char*)xl + 5120000);
    u16*   m2h    = (u16*)((char*)xl + 10240000);
    u16*   m2l    = (u16*)((char*)xl + 15360000);
    float* logits = (float*)xr;

    detect_kernel<<<1, 256, 0, stream>>>(ei, (const u16*)x, flag);
    zero_counts_kernel<<<(N_NODES + 255) / 256, 256, 0, stream>>>(counts);
    count_edges_kernel<<<(N_EDGES + 255) / 256, 256, 0, stream>>>(ei, flag, counts);
    scan_counts_kernel<<<1, 256, 0, stream>>>(counts, rowptr);
    fill_esrcp_kernel<<<(N_EDGES + 255) / 256, 256, 0, stream>>>(ei, flag, counts, esrcp);

    dim3 g512(D_EMB / 64, (N_NODES + 63) / 64);
    dim3 g256(D_HID / 64, (N_NODES + 63) / 64);

    gemm_kernel<0, 0><<<g512, 256, 0, stream>>>(x, nullptr, nullptr, Wl[0], xl, nullptr, nullptr, nullptr, flag, N_NODES, D_EMB, D_IN);
    gemm_kernel<0, 0><<<g512, 256, 0, stream>>>(x, nullptr, nullptr, Wr[0], xr, nullptr, nullptr, nullptr, flag, N_NODES, D_EMB, D_IN);
    gat_edge_kernel<<<N_NODES, 256, 0, stream>>>(rowptr, esrcp, xl, xr, att[0], bia[0], flag, hh, hl);

    for (int L = 1; L < 3; L++) {
        gemm_kernel<0, 1><<<g512, 256, 0, stream>>>(nullptr, hh, hl, Wl[L], xl, nullptr, nullptr, nullptr, flag, N_NODES, D_EMB, D_EMB);
        gemm_kernel<0, 1><<<g512, 256, 0, stream>>>(nullptr, hh, hl, Wr[L], xr, nullptr, nullptr, nullptr, flag, N_NODES, D_EMB, D_EMB);
        gat_edge_kernel<<<N_NODES, 256, 0, stream>>>(rowptr, esrcp, xl, xr, att[L], bia[L], flag, hh, hl);
    }

    gemm_kernel<1, 1><<<g256, 256, 0, stream>>>(nullptr, hh, hl, A1, nullptr, m1h, m1l, c1, flag, N_NODES, D_HID, D_EMB);
    gemm_kernel<1, 1><<<g256, 256, 0, stream>>>(nullptr, m1h, m1l, A2, nullptr, m2h, m2l, c2, flag, N_NODES, D_HID, D_HID);
    logit_kernel<<<(N_NODES + 3) / 4, 256, 0, stream>>>(m2h, m2l, A3, c3, flag, logits);
    softmax_kernel<<<1, 256, 0, stream>>>(logits, (float*)d_out);
}

// Round 7
// 623.218 us; speedup vs baseline: 1.4787x; 1.2072x over previous
//
#include <hip/hip_runtime.h>
#include <hip/hip_bf16.h>

#define N_NODES 10000
#define N_EDGES 160000
#define D_IN    128
#define D_EMB   512
#define D_HID   256

typedef unsigned short u16;
typedef __attribute__((ext_vector_type(8))) short short8;
typedef __attribute__((ext_vector_type(4))) float floatx4;

__device__ __forceinline__ float bf2f(u16 u) {
    union { unsigned int i; float f; } v; v.i = ((unsigned int)u) << 16; return v.f;
}
__device__ __forceinline__ u16 f2bf(float f) {
    union { float f; unsigned int i; } v; v.f = f;
    unsigned int x = v.i;
    return (u16)((x + 0x7fffu + ((x >> 16) & 1u)) >> 16);  // RNE
}
__device__ __forceinline__ float inval(const void* p, int fp32, int idx) {
    return fp32 ? ((const float*)p)[idx] : bf2f(((const u16*)p)[idx]);
}

// flag[0]: edge_index is int64-viewed-as-int32-pairs; flag[1]: floats are fp32
__device__ __forceinline__ int edge_src(const int* __restrict__ ei, int flg, int e) {
    int v = flg ? ei[2 * e] : ei[e];
    return min(max(v, 0), N_NODES - 1);
}
__device__ __forceinline__ int edge_dst(const int* __restrict__ ei, int flg, int e) {
    int v = flg ? ei[2 * N_EDGES + 2 * e] : ei[N_EDGES + e];
    return min(max(v, 0), N_NODES - 1);
}

// ---------------------------------------------------------------------------
__global__ void sentinel_kernel(float* out, int n) {
    int i = blockIdx.x * 256 + threadIdx.x;
    if (i < n) out[i] = 1.0f;   // => workspace too small for pair buffers
}

__global__ __launch_bounds__(256)
void detect_kernel(const int* __restrict__ ei, const u16* __restrict__ xu, int* flag) {
    __shared__ int s_or[256];
    __shared__ int s_cnt[256];
    int t = threadIdx.x;
    int v = 0;
    for (int k = t; k < 4096; k += 256) v |= ei[1 + 2 * k];
    int c = 0;
    for (int k = t; k < 4096; k += 256) {
        u16 u = xu[k];
        int ex = (u >> 7) & 0xFF;
        bool plaus = (u == 0) || (ex >= 64 && ex <= 191);
        if (!plaus) c++;
    }
    s_or[t] = v; s_cnt[t] = c;
    __syncthreads();
    for (int off = 128; off > 0; off >>= 1) {
        if (t < off) { s_or[t] |= s_or[t + off]; s_cnt[t] += s_cnt[t + off]; }
        __syncthreads();
    }
    if (t == 0) {
        flag[0] = (s_or[0] == 0) ? 1 : 0;
        flag[1] = (s_cnt[0] > 256) ? 1 : 0;
    }
}

// ---------------------------------------------------------------------------
// Preconvert a float-tensor matrix [rows,cols] into bf16 hi/lo pair.
// TRANSPOSE=1: output [cols,rows] (for GEMM B operands -> [N,K] row-major).
// ---------------------------------------------------------------------------
template<int TRANSPOSE>
__global__ __launch_bounds__(256)
void convert_kernel(const void* __restrict__ src, const int* __restrict__ flag,
                    u16* __restrict__ dh, u16* __restrict__ dl, int rows, int cols)
{
    int idx = blockIdx.x * 256 + threadIdx.x;
    int total = rows * cols;
    if (idx >= total) return;
    int fp32 = flag[1];
    float v = inval(src, fp32, idx);
    u16 hi = f2bf(v);
    u16 lo = f2bf(v - bf2f(hi));
    int o;
    if (TRANSPOSE) { int r = idx / cols, c = idx % cols; o = c * rows + r; }
    else o = idx;
    dh[o] = hi; dl[o] = lo;
}

// ---------------------------------------------------------------------------
// CSR build
// ---------------------------------------------------------------------------
__global__ void zero_counts_kernel(int* counts) {
    int i = blockIdx.x * 256 + threadIdx.x;
    if (i < N_NODES) counts[i] = 0;
}

__global__ void count_edges_kernel(const int* __restrict__ ei, const int* __restrict__ flag,
                                   int* counts) {
    int e = blockIdx.x * 256 + threadIdx.x;
    if (e < N_EDGES) atomicAdd(&counts[edge_dst(ei, flag[0], e)], 1);
}

__global__ __launch_bounds__(256)
void scan_counts_kernel(int* counts, int* rowptr) {
    __shared__ int part[256];
    int tid = threadIdx.x;
    const int CH = 40;
    int base = tid * CH;
    int loc[CH];
    int s = 0;
    #pragma unroll
    for (int i = 0; i < CH; i++) {
        int idx = base + i;
        int c = (idx < N_NODES) ? counts[idx] : 0;
        loc[i] = s; s += c;
    }
    part[tid] = s;
    __syncthreads();
    for (int off = 1; off < 256; off <<= 1) {
        int v = part[tid];
        int add = (tid >= off) ? part[tid - off] : 0;
        __syncthreads();
        part[tid] = v + add;
        __syncthreads();
    }
    int pre = (tid > 0) ? part[tid - 1] : 0;
    #pragma unroll
    for (int i = 0; i < CH; i++) {
        int idx = base + i;
        if (idx < N_NODES) { int v = pre + loc[i]; rowptr[idx] = v; counts[idx] = v; }
    }
    if (tid == 255) rowptr[N_NODES] = part[255];
}

__global__ void fill_esrcp_kernel(const int* __restrict__ ei, const int* __restrict__ flag,
                                  int* counts, int* esrcp) {
    int e = blockIdx.x * 256 + threadIdx.x;
    if (e < N_EDGES) {
        int flg = flag[0];
        int pos = atomicAdd(&counts[edge_dst(ei, flg, e)], 1);
        if (pos >= 0 && pos < N_EDGES) esrcp[pos] = edge_src(ei, flg, e);
    }
}

// ---------------------------------------------------------------------------
// 128x128-tile pair GEMM: C[M,N] = (Ah+Al)[M,K] @ (Bh+Bl)^T-stored[N,K]
// 3 MFMAs per tile: Ah*Bh + Al*Bh + Ah*Bl (Al*Bl ~1e-5 rel, dropped).
// mode 0: store fp32 C. mode 1: bias + leakyrelu(0.1) -> hi/lo bf16 pair.
// Grid: (N/128, ceil(M/128)), 256 threads (4 waves, 2x2; 4x4 16x16x32 accs each).
// ---------------------------------------------------------------------------
__global__ __launch_bounds__(256)
void gemm_pair_kernel(const u16* __restrict__ Ah, const u16* __restrict__ Al,
                      const u16* __restrict__ BTh, const u16* __restrict__ BTl,
                      float* __restrict__ Cf, u16* __restrict__ Ch, u16* __restrict__ Cl,
                      const void* __restrict__ biasraw, const int* __restrict__ flag,
                      int M, int N, int K, int mode)
{
    __shared__ u16 sAh[128 * 40];
    __shared__ u16 sAl[128 * 40];
    __shared__ u16 sBh[128 * 40];
    __shared__ u16 sBl[128 * 40];
    int tid = threadIdx.x;
    int lane = tid & 63, wv = tid >> 6;
    int l15 = lane & 15, l4 = lane >> 4;
    int wr = (wv >> 1) * 64, wc = (wv & 1) * 64;
    int m0 = blockIdx.y * 128, n0 = blockIdx.x * 128;

    floatx4 acc[4][4];
    #pragma unroll
    for (int i = 0; i < 4; i++)
        #pragma unroll
        for (int j = 0; j < 4; j++) acc[i][j] = (floatx4){0.f, 0.f, 0.f, 0.f};

    for (int kk = 0; kk < K; kk += 32) {
        __syncthreads();
        #pragma unroll
        for (int p = 0; p < 2; p++) {
            int idx = tid + p * 256;
            int srow = idx >> 2, skc = (idx & 3) * 8;
            int gr = min(m0 + srow, M - 1);
            *(uint4*)(&sAh[srow * 40 + skc]) = *(const uint4*)(Ah + (size_t)gr * K + kk + skc);
            *(uint4*)(&sAl[srow * 40 + skc]) = *(const uint4*)(Al + (size_t)gr * K + kk + skc);
            int gn = n0 + srow;   // N is a multiple of 128 -> in bounds
            *(uint4*)(&sBh[srow * 40 + skc]) = *(const uint4*)(BTh + (size_t)gn * K + kk + skc);
            *(uint4*)(&sBl[srow * 40 + skc]) = *(const uint4*)(BTl + (size_t)gn * K + kk + skc);
        }
        __syncthreads();

        short8 ah[4], al[4];
        #pragma unroll
        for (int i = 0; i < 4; i++) {
            int arow = wr + i * 16 + l15;
            ah[i] = *(const short8*)(&sAh[arow * 40 + l4 * 8]);
            al[i] = *(const short8*)(&sAl[arow * 40 + l4 * 8]);
        }
        #pragma unroll
        for (int j = 0; j < 4; j++) {
            int bcol = wc + j * 16 + l15;
            short8 bh = *(const short8*)(&sBh[bcol * 40 + l4 * 8]);
            short8 bl = *(const short8*)(&sBl[bcol * 40 + l4 * 8]);
            #pragma unroll
            for (int i = 0; i < 4; i++) {
                acc[i][j] = __builtin_amdgcn_mfma_f32_16x16x32_bf16(ah[i], bh, acc[i][j], 0, 0, 0);
                acc[i][j] = __builtin_amdgcn_mfma_f32_16x16x32_bf16(al[i], bh, acc[i][j], 0, 0, 0);
                acc[i][j] = __builtin_amdgcn_mfma_f32_16x16x32_bf16(ah[i], bl, acc[i][j], 0, 0, 0);
            }
        }
    }

    const int fp32 = flag[1];
    #pragma unroll
    for (int j = 0; j < 4; j++) {
        int col = n0 + wc + j * 16 + l15;
        float bv = (mode == 1) ? inval(biasraw, fp32, col) : 0.f;
        #pragma unroll
        for (int i = 0; i < 4; i++) {
            #pragma unroll
            for (int r = 0; r < 4; r++) {
                int row = m0 + wr + i * 16 + l4 * 4 + r;
                if (row < M) {
                    float v = acc[i][j][r];
                    if (mode == 0) {
                        Cf[(size_t)row * N + col] = v;
                    } else {
                        v += bv;
                        v = v > 0.f ? v : 0.1f * v;
                        u16 hi = f2bf(v);
                        Ch[(size_t)row * N + col] = hi;
                        Cl[(size_t)row * N + col] = f2bf(v - bf2f(hi));
                    }
                }
            }
        }
    }
}

// ---------------------------------------------------------------------------
// GATv2: wave-per-node, single-pass online-softmax aggregation.
// Each lane owns 8 dims (lane*8..+7). No LDS, no __syncthreads.
// ---------------------------------------------------------------------------
__global__ __launch_bounds__(256)
void gat_wave_kernel(const int* __restrict__ rowptr, const int* __restrict__ esrcp,
                     const float* __restrict__ xl, const float* __restrict__ xr,
                     const void* __restrict__ att, const void* __restrict__ bias,
                     const int* __restrict__ flag,
                     u16* __restrict__ hh, u16* __restrict__ hl)
{
    int lane = threadIdx.x & 63, wv = threadIdx.x >> 6;
    int n = blockIdx.x * 4 + wv;
    if (n >= N_NODES) return;
    int fp32 = flag[1];
    int d0 = lane * 8;

    const float* xrr = xr + (size_t)n * D_EMB;
    float4 r0 = *(const float4*)(xrr + d0);
    float4 r1 = *(const float4*)(xrr + d0 + 4);
    float xrv[8] = {r0.x, r0.y, r0.z, r0.w, r1.x, r1.y, r1.z, r1.w};
    float attv[8];
    #pragma unroll
    for (int k = 0; k < 8; k++) attv[k] = inval(att, fp32, d0 + k);

    int beg = rowptr[n], end = rowptr[n + 1];
    float m_run = -3.4e38f, s_run = 0.f;
    float acc[8] = {0.f, 0.f, 0.f, 0.f, 0.f, 0.f, 0.f, 0.f};

    for (int j = beg; j < end; j++) {
        int s = esrcp[j];
        const float* xs = xl + (size_t)s * D_EMB;
        float4 v0 = *(const float4*)(xs + d0);
        float4 v1 = *(const float4*)(xs + d0 + 4);
        float v[8] = {v0.x, v0.y, v0.z, v0.w, v1.x, v1.y, v1.z, v1.w};
        float e = 0.f;
        #pragma unroll
        for (int k = 0; k < 8; k++) {
            float t = v[k] + xrv[k];
            t = t > 0.f ? t : 0.2f * t;
            e += attv[k] * t;
        }
        #pragma unroll
        for (int o = 32; o > 0; o >>= 1) e += __shfl_xor(e, o);

        float mnew = fmaxf(m_run, e);
        float scale = __expf(m_run - mnew);   // first edge: exp(-huge) = 0
        float w = __expf(e - mnew);
        s_run = s_run * scale + w;
        #pragma unroll
        for (int k = 0; k < 8; k++) acc[k] = acc[k] * scale + w * v[k];
        m_run = mnew;
    }

    float inv = 1.f / (s_run + 1e-16f);
    union { uint4 q; u16 us[8]; } ph, pl;
    #pragma unroll
    for (int k = 0; k < 8; k++) {
        float h = tanhf(acc[k] * inv + inval(bias, fp32, d0 + k));
        u16 hi = f2bf(h);
        ph.us[k] = hi;
        pl.us[k] = f2bf(h - bf2f(hi));
    }
    *(uint4*)(&hh[(size_t)n * D_EMB + d0]) = ph.q;
    *(uint4*)(&hl[(size_t)n * D_EMB + d0]) = pl.q;
}

// ---------------------------------------------------------------------------
__global__ __launch_bounds__(256)
void logit_kernel(const u16* __restrict__ m2h, const u16* __restrict__ m2l,
                  const void* __restrict__ A3, const void* __restrict__ c3,
                  const int* __restrict__ flag,
                  float* __restrict__ logits)
{
    int tid = threadIdx.x, lane = tid & 63, wv = tid >> 6;
    int node = blockIdx.x * 4 + wv;
    if (node >= N_NODES) return;
    int fp32 = flag[1];
    const u16* rh = m2h + (size_t)node * D_HID;
    const u16* rl = m2l + (size_t)node * D_HID;
    int d0 = lane * 4;
    float a = 0.f;
    #pragma unroll
    for (int j = 0; j < 4; j++) {
        float hv = bf2f(rh[d0 + j]) + bf2f(rl[d0 + j]);
        a += hv * inval(A3, fp32, d0 + j);
    }
    #pragma unroll
    for (int o = 32; o > 0; o >>= 1) a += __shfl_down(a, o);
    if (lane == 0) logits[node] = a + inval(c3, fp32, 0);
}

// ---------------------------------------------------------------------------
__global__ __launch_bounds__(256)
void softmax_kernel(const float* __restrict__ logits, float* __restrict__ out)
{
    __shared__ float red[4];
    __shared__ float s_m, s_s;
    int tid = threadIdx.x, lane = tid & 63, wv = tid >> 6;
    float m = -3.4e38f;
    for (int i = tid; i < N_NODES; i += 256) m = fmaxf(m, logits[i]);
    #pragma unroll
    for (int o = 32; o > 0; o >>= 1) m = fmaxf(m, __shfl_down(m, o));
    if (lane == 0) red[wv] = m;
    __syncthreads();
    if (tid == 0) {
        float mm = red[0];
        for (int i = 1; i < 4; i++) mm = fmaxf(mm, red[i]);
        s_m = mm;
    }
    __syncthreads();
    float mm = s_m;
    float s = 0.f;
    for (int i = tid; i < N_NODES; i += 256) s += __expf(logits[i] - mm);
    #pragma unroll
    for (int o = 32; o > 0; o >>= 1) s += __shfl_down(s, o);
    if (lane == 0) red[wv] = s;
    __syncthreads();
    if (tid == 0) {
        float ss = 0.f;
        for (int i = 0; i < 4; i++) ss += red[i];
        s_s = ss;
    }
    __syncthreads();
    float invs = 1.f / s_s;
    for (int i = tid; i < N_NODES; i += 256) out[i] = __expf(logits[i] - mm) * invs;
}

// ---------------------------------------------------------------------------
extern "C" void kernel_launch(void* const* d_in, const int* in_sizes, int n_in,
                              void* d_out, int out_size, void* d_ws, size_t ws_size,
                              hipStream_t stream)
{
    const void* x   = d_in[0];
    const int*  ei  = (const int*)d_in[1];
    const void* Wl[3]  = {d_in[2],  d_in[6],  d_in[10]};
    const void* Wr[3]  = {d_in[3],  d_in[7],  d_in[11]};
    const void* att[3] = {d_in[4],  d_in[8],  d_in[12]};
    const void* bia[3] = {d_in[5],  d_in[9],  d_in[13]};
    const void* A1 = d_in[14];
    const void* c1 = d_in[15];
    const void* A2 = d_in[16];
    const void* c2 = d_in[17];
    const void* A3 = d_in[18];
    const void* c3 = d_in[19];

    char* p = (char*)d_ws;
    auto alloc = [&](size_t bytes) {
        char* r = p;
        p += (bytes + 255) & ~(size_t)255;
        return r;
    };
    float* xl     = (float*)alloc((size_t)N_NODES * D_EMB * 4);   // 20.48 MB
    float* xr     = (float*)alloc((size_t)N_NODES * D_EMB * 4);   // 20.48 MB
    u16*   hh     = (u16*)  alloc((size_t)N_NODES * D_EMB * 2);   // 10.24 MB
    u16*   hl     = (u16*)  alloc((size_t)N_NODES * D_EMB * 2);   // 10.24 MB
    int*   esrcp  = (int*)  alloc((size_t)N_EDGES * 4);
    int*   rowptr = (int*)  alloc((size_t)(N_NODES + 1) * 4);
    int*   counts = (int*)  alloc((size_t)N_NODES * 4);
    int*   flag   = (int*)  alloc(256);
    // preconverted transposed weight pairs [N,K]
    u16* wl1h = (u16*)alloc(D_EMB * D_IN  * 2); u16* wl1l = (u16*)alloc(D_EMB * D_IN  * 2);
    u16* wr1h = (u16*)alloc(D_EMB * D_IN  * 2); u16* wr1l = (u16*)alloc(D_EMB * D_IN  * 2);
    u16* wl2h = (u16*)alloc(D_EMB * D_EMB * 2); u16* wl2l = (u16*)alloc(D_EMB * D_EMB * 2);
    u16* wr2h = (u16*)alloc(D_EMB * D_EMB * 2); u16* wr2l = (u16*)alloc(D_EMB * D_EMB * 2);
    u16* wl3h = (u16*)alloc(D_EMB * D_EMB * 2); u16* wl3l = (u16*)alloc(D_EMB * D_EMB * 2);
    u16* wr3h = (u16*)alloc(D_EMB * D_EMB * 2); u16* wr3l = (u16*)alloc(D_EMB * D_EMB * 2);
    u16* a1h  = (u16*)alloc(D_EMB * D_HID * 2); u16* a1l  = (u16*)alloc(D_EMB * D_HID * 2);
    u16* a2h  = (u16*)alloc(D_HID * D_HID * 2); u16* a2l  = (u16*)alloc(D_HID * D_HID * 2);
    size_t needed = (size_t)(p - (char*)d_ws);   // ~67.5 MB

    if (ws_size < needed) {
        sentinel_kernel<<<(out_size + 255) / 256, 256, 0, stream>>>((float*)d_out, out_size);
        return;
    }

    // x pair lives in hh/hl (dead until gat1); MLP buffers alias xl; logits alias xr.
    u16* xph = hh;                         // [N_NODES, D_IN] pair: 2.56 MB each
    u16* xpl = hl;
    u16* m1h = (u16*)xl;
    u16* m1l = (u16*)((char*)xl + 5120000);
    u16* m2h = (u16*)((char*)xl + 10240000);
    u16* m2l = (u16*)((char*)xl + 15360000);
    float* logits = (float*)xr;

    detect_kernel<<<1, 256, 0, stream>>>(ei, (const u16*)x, flag);

    // CSR
    zero_counts_kernel<<<(N_NODES + 255) / 256, 256, 0, stream>>>(counts);
    count_edges_kernel<<<(N_EDGES + 255) / 256, 256, 0, stream>>>(ei, flag, counts);
    scan_counts_kernel<<<1, 256, 0, stream>>>(counts, rowptr);
    fill_esrcp_kernel<<<(N_EDGES + 255) / 256, 256, 0, stream>>>(ei, flag, counts, esrcp);

    // preconversions
    convert_kernel<0><<<(N_NODES * D_IN + 255) / 256, 256, 0, stream>>>(x, flag, xph, xpl, N_NODES, D_IN);
    convert_kernel<1><<<(D_IN * D_EMB + 255) / 256, 256, 0, stream>>>(Wl[0], flag, wl1h, wl1l, D_IN, D_EMB);
    convert_kernel<1><<<(D_IN * D_EMB + 255) / 256, 256, 0, stream>>>(Wr[0], flag, wr1h, wr1l, D_IN, D_EMB);
    convert_kernel<1><<<(D_EMB * D_EMB + 255) / 256, 256, 0, stream>>>(Wl[1], flag, wl2h, wl2l, D_EMB, D_EMB);
    convert_kernel<1><<<(D_EMB * D_EMB + 255) / 256, 256, 0, stream>>>(Wr[1], flag, wr2h, wr2l, D_EMB, D_EMB);
    convert_kernel<1><<<(D_EMB * D_EMB + 255) / 256, 256, 0, stream>>>(Wl[2], flag, wl3h, wl3l, D_EMB, D_EMB);
    convert_kernel<1><<<(D_EMB * D_EMB + 255) / 256, 256, 0, stream>>>(Wr[2], flag, wr3h, wr3l, D_EMB, D_EMB);
    convert_kernel<1><<<(D_EMB * D_HID + 255) / 256, 256, 0, stream>>>(A1, flag, a1h, a1l, D_EMB, D_HID);
    convert_kernel<1><<<(D_HID * D_HID + 255) / 256, 256, 0, stream>>>(A2, flag, a2h, a2l, D_HID, D_HID);

    dim3 gemm512(D_EMB / 128, (N_NODES + 127) / 128);   // (4, 79)
    dim3 gemm256(D_HID / 128, (N_NODES + 127) / 128);   // (2, 79)

    // layer 1
    gemm_pair_kernel<<<gemm512, 256, 0, stream>>>(xph, xpl, wl1h, wl1l, xl, nullptr, nullptr, nullptr, flag, N_NODES, D_EMB, D_IN, 0);
    gemm_pair_kernel<<<gemm512, 256, 0, stream>>>(xph, xpl, wr1h, wr1l, xr, nullptr, nullptr, nullptr, flag, N_NODES, D_EMB, D_IN, 0);
    gat_wave_kernel<<<(N_NODES + 3) / 4, 256, 0, stream>>>(rowptr, esrcp, xl, xr, att[0], bia[0], flag, hh, hl);

    // layer 2
    gemm_pair_kernel<<<gemm512, 256, 0, stream>>>(hh, hl, wl2h, wl2l, xl, nullptr, nullptr, nullptr, flag, N_NODES, D_EMB, D_EMB, 0);
    gemm_pair_kernel<<<gemm512, 256, 0, stream>>>(hh, hl, wr2h, wr2l, xr, nullptr, nullptr, nullptr, flag, N_NODES, D_EMB, D_EMB, 0);
    gat_wave_kernel<<<(N_NODES + 3) / 4, 256, 0, stream>>>(rowptr, esrcp, xl, xr, att[1], bia[1], flag, hh, hl);

    // layer 3
    gemm_pair_kernel<<<gemm512, 256, 0, stream>>>(hh, hl, wl3h, wl3l, xl, nullptr, nullptr, nullptr, flag, N_NODES, D_EMB, D_EMB, 0);
    gemm_pair_kernel<<<gemm512, 256, 0, stream>>>(hh, hl, wr3h, wr3l, xr, nullptr, nullptr, nullptr, flag, N_NODES, D_EMB, D_EMB, 0);
    gat_wave_kernel<<<(N_NODES + 3) / 4, 256, 0, stream>>>(rowptr, esrcp, xl, xr, att[2], bia[2], flag, hh, hl);

    // MLP
    gemm_pair_kernel<<<gemm256, 256, 0, stream>>>(hh, hl, a1h, a1l, nullptr, m1h, m1l, c1, flag, N_NODES, D_HID, D_EMB, 1);
    gemm_pair_kernel<<<gemm256, 256, 0, stream>>>(m1h, m1l, a2h, a2l, nullptr, m2h, m2l, c2, flag, N_NODES, D_HID, D_HID, 1);
    logit_kernel<<<(N_NODES + 3) / 4, 256, 0, stream>>>(m2h, m2l, A3, c3, flag, logits);
    softmax_kernel<<<1, 256, 0, stream>>>(logits, (float*)d_out);
}

// Round 8
// 540.835 us; speedup vs baseline: 1.7040x; 1.1523x over previous
//
#include <hip/hip_runtime.h>
#include <hip/hip_bf16.h>

#define N_NODES 10000
#define N_EDGES 160000
#define D_IN    128
#define D_EMB   512
#define D_HID   256

typedef unsigned short u16;
typedef __attribute__((ext_vector_type(8))) short short8;
typedef __attribute__((ext_vector_type(4))) float floatx4;

__device__ __forceinline__ float bf2f(u16 u) {
    union { unsigned int i; float f; } v; v.i = ((unsigned int)u) << 16; return v.f;
}
__device__ __forceinline__ u16 f2bf(float f) {
    union { float f; unsigned int i; } v; v.f = f;
    unsigned int x = v.i;
    return (u16)((x + 0x7fffu + ((x >> 16) & 1u)) >> 16);  // RNE
}
__device__ __forceinline__ float inval(const void* p, int fp32, int idx) {
    return fp32 ? ((const float*)p)[idx] : bf2f(((const u16*)p)[idx]);
}

// flag[0]: edge_index is int64-viewed-as-int32-pairs; flag[1]: floats are fp32
__device__ __forceinline__ int edge_src(const int* __restrict__ ei, int flg, int e) {
    int v = flg ? ei[2 * e] : ei[e];
    return min(max(v, 0), N_NODES - 1);
}
__device__ __forceinline__ int edge_dst(const int* __restrict__ ei, int flg, int e) {
    int v = flg ? ei[2 * N_EDGES + 2 * e] : ei[N_EDGES + e];
    return min(max(v, 0), N_NODES - 1);
}

// ---------------------------------------------------------------------------
__global__ void sentinel_kernel(float* out, int n) {
    int i = blockIdx.x * 256 + threadIdx.x;
    if (i < n) out[i] = 1.0f;   // => workspace too small
}

__global__ __launch_bounds__(256)
void detect_kernel(const int* __restrict__ ei, const u16* __restrict__ xu, int* flag) {
    __shared__ int s_or[256];
    __shared__ int s_cnt[256];
    int t = threadIdx.x;
    int v = 0;
    for (int k = t; k < 4096; k += 256) v |= ei[1 + 2 * k];
    int c = 0;
    for (int k = t; k < 4096; k += 256) {
        u16 u = xu[k];
        int ex = (u >> 7) & 0xFF;
        bool plaus = (u == 0) || (ex >= 64 && ex <= 191);
        if (!plaus) c++;
    }
    s_or[t] = v; s_cnt[t] = c;
    __syncthreads();
    for (int off = 128; off > 0; off >>= 1) {
        if (t < off) { s_or[t] |= s_or[t + off]; s_cnt[t] += s_cnt[t + off]; }
        __syncthreads();
    }
    if (t == 0) {
        flag[0] = (s_or[0] == 0) ? 1 : 0;
        flag[1] = (s_cnt[0] > 256) ? 1 : 0;
    }
}

// ---------------------------------------------------------------------------
// Fused preconversion: all float-tensor inputs -> bf16 hi/lo pairs, one dispatch.
// ---------------------------------------------------------------------------
struct ConvJobs {
    const void* src[10];
    u16* dh[10];
    u16* dl[10];
    int rows[10], cols[10], trans[10];
    int cum[11];
    int njobs;
};

__global__ __launch_bounds__(256)
void convert_fused_kernel(ConvJobs jobs, const int* __restrict__ flag) {
    int idx = blockIdx.x * 256 + threadIdx.x;
    if (idx >= jobs.cum[jobs.njobs]) return;
    int fp32 = flag[1];
    int jb = 0;
    while (idx >= jobs.cum[jb + 1]) jb++;
    int local = idx - jobs.cum[jb];
    float v = inval(jobs.src[jb], fp32, local);
    u16 hi = f2bf(v);
    u16 lo = f2bf(v - bf2f(hi));
    int o;
    if (jobs.trans[jb]) {
        int r = local / jobs.cols[jb], c = local % jobs.cols[jb];
        o = c * jobs.rows[jb] + r;
    } else o = local;
    jobs.dh[jb][o] = hi;
    jobs.dl[jb][o] = lo;
}

// ---------------------------------------------------------------------------
// CSR build
// ---------------------------------------------------------------------------
__global__ void zero_counts_kernel(int* counts) {
    int i = blockIdx.x * 256 + threadIdx.x;
    if (i < N_NODES) counts[i] = 0;
}

__global__ void count_edges_kernel(const int* __restrict__ ei, const int* __restrict__ flag,
                                   int* counts) {
    int e = blockIdx.x * 256 + threadIdx.x;
    if (e < N_EDGES) atomicAdd(&counts[edge_dst(ei, flag[0], e)], 1);
}

__global__ __launch_bounds__(256)
void scan_counts_kernel(int* counts, int* rowptr) {
    __shared__ int part[256];
    int tid = threadIdx.x;
    const int CH = 40;
    int base = tid * CH;
    int loc[CH];
    int s = 0;
    #pragma unroll
    for (int i = 0; i < CH; i++) {
        int idx = base + i;
        int c = (idx < N_NODES) ? counts[idx] : 0;
        loc[i] = s; s += c;
    }
    part[tid] = s;
    __syncthreads();
    for (int off = 1; off < 256; off <<= 1) {
        int v = part[tid];
        int add = (tid >= off) ? part[tid - off] : 0;
        __syncthreads();
        part[tid] = v + add;
        __syncthreads();
    }
    int pre = (tid > 0) ? part[tid - 1] : 0;
    #pragma unroll
    for (int i = 0; i < CH; i++) {
        int idx = base + i;
        if (idx < N_NODES) { int v = pre + loc[i]; rowptr[idx] = v; counts[idx] = v; }
    }
    if (tid == 255) rowptr[N_NODES] = part[255];
}

__global__ void fill_esrcp_kernel(const int* __restrict__ ei, const int* __restrict__ flag,
                                  int* counts, int* esrcp) {
    int e = blockIdx.x * 256 + threadIdx.x;
    if (e < N_EDGES) {
        int flg = flag[0];
        int pos = atomicAdd(&counts[edge_dst(ei, flg, e)], 1);
        if (pos >= 0 && pos < N_EDGES) esrcp[pos] = edge_src(ei, flg, e);
    }
}

// ---------------------------------------------------------------------------
// Dual 128x128-tile pair GEMM: both Wl and Wr in one dispatch.
// blockIdx.x in [0, 2*N/128): low half -> B0/C0, high half -> B1/C1.
// C = (Ah+Al)[M,K] @ (Bh+Bl)^T-stored[N,K]; 3 MFMAs/tile, fp32 C.
// ---------------------------------------------------------------------------
__global__ __launch_bounds__(256)
void gemm_dual_kernel(const u16* __restrict__ Ah, const u16* __restrict__ Al,
                      const u16* __restrict__ B0h, const u16* __restrict__ B0l,
                      const u16* __restrict__ B1h, const u16* __restrict__ B1l,
                      float* __restrict__ C0, float* __restrict__ C1,
                      int M, int N, int K)
{
    __shared__ u16 sAh[128 * 40];
    __shared__ u16 sAl[128 * 40];
    __shared__ u16 sBh[128 * 40];
    __shared__ u16 sBl[128 * 40];
    int nb = N >> 7;
    int half = (int)blockIdx.x >= nb;
    int bx = half ? (blockIdx.x - nb) : blockIdx.x;
    const u16* BTh = half ? B1h : B0h;
    const u16* BTl = half ? B1l : B0l;
    float* Cf = half ? C1 : C0;

    int tid = threadIdx.x;
    int lane = tid & 63, wv = tid >> 6;
    int l15 = lane & 15, l4 = lane >> 4;
    int wr = (wv >> 1) * 64, wc = (wv & 1) * 64;
    int m0 = blockIdx.y * 128, n0 = bx * 128;

    floatx4 acc[4][4];
    #pragma unroll
    for (int i = 0; i < 4; i++)
        #pragma unroll
        for (int j = 0; j < 4; j++) acc[i][j] = (floatx4){0.f, 0.f, 0.f, 0.f};

    for (int kk = 0; kk < K; kk += 32) {
        __syncthreads();
        #pragma unroll
        for (int p = 0; p < 2; p++) {
            int idx = tid + p * 256;
            int srow = idx >> 2, skc = (idx & 3) * 8;
            int gr = min(m0 + srow, M - 1);
            *(uint4*)(&sAh[srow * 40 + skc]) = *(const uint4*)(Ah + (size_t)gr * K + kk + skc);
            *(uint4*)(&sAl[srow * 40 + skc]) = *(const uint4*)(Al + (size_t)gr * K + kk + skc);
            int gn = n0 + srow;
            *(uint4*)(&sBh[srow * 40 + skc]) = *(const uint4*)(BTh + (size_t)gn * K + kk + skc);
            *(uint4*)(&sBl[srow * 40 + skc]) = *(const uint4*)(BTl + (size_t)gn * K + kk + skc);
        }
        __syncthreads();

        short8 ah[4], al[4];
        #pragma unroll
        for (int i = 0; i < 4; i++) {
            int arow = wr + i * 16 + l15;
            ah[i] = *(const short8*)(&sAh[arow * 40 + l4 * 8]);
            al[i] = *(const short8*)(&sAl[arow * 40 + l4 * 8]);
        }
        #pragma unroll
        for (int j = 0; j < 4; j++) {
            int bcol = wc + j * 16 + l15;
            short8 bh = *(const short8*)(&sBh[bcol * 40 + l4 * 8]);
            short8 bl = *(const short8*)(&sBl[bcol * 40 + l4 * 8]);
            #pragma unroll
            for (int i = 0; i < 4; i++) {
                acc[i][j] = __builtin_amdgcn_mfma_f32_16x16x32_bf16(ah[i], bh, acc[i][j], 0, 0, 0);
                acc[i][j] = __builtin_amdgcn_mfma_f32_16x16x32_bf16(al[i], bh, acc[i][j], 0, 0, 0);
                acc[i][j] = __builtin_amdgcn_mfma_f32_16x16x32_bf16(ah[i], bl, acc[i][j], 0, 0, 0);
            }
        }
    }

    #pragma unroll
    for (int j = 0; j < 4; j++) {
        int col = n0 + wc + j * 16 + l15;
        #pragma unroll
        for (int i = 0; i < 4; i++) {
            #pragma unroll
            for (int r = 0; r < 4; r++) {
                int row = m0 + wr + i * 16 + l4 * 4 + r;
                if (row < M) Cf[(size_t)row * N + col] = acc[i][j][r];
            }
        }
    }
}

// ---------------------------------------------------------------------------
// Single pair GEMM for the MLP (mode: bias + leakyrelu(0.1) -> hi/lo pair)
// ---------------------------------------------------------------------------
__global__ __launch_bounds__(256)
void gemm_pair_kernel(const u16* __restrict__ Ah, const u16* __restrict__ Al,
                      const u16* __restrict__ BTh, const u16* __restrict__ BTl,
                      u16* __restrict__ Ch, u16* __restrict__ Cl,
                      const void* __restrict__ biasraw, const int* __restrict__ flag,
                      int M, int N, int K)
{
    __shared__ u16 sAh[128 * 40];
    __shared__ u16 sAl[128 * 40];
    __shared__ u16 sBh[128 * 40];
    __shared__ u16 sBl[128 * 40];
    int tid = threadIdx.x;
    int lane = tid & 63, wv = tid >> 6;
    int l15 = lane & 15, l4 = lane >> 4;
    int wr = (wv >> 1) * 64, wc = (wv & 1) * 64;
    int m0 = blockIdx.y * 128, n0 = blockIdx.x * 128;

    floatx4 acc[4][4];
    #pragma unroll
    for (int i = 0; i < 4; i++)
        #pragma unroll
        for (int j = 0; j < 4; j++) acc[i][j] = (floatx4){0.f, 0.f, 0.f, 0.f};

    for (int kk = 0; kk < K; kk += 32) {
        __syncthreads();
        #pragma unroll
        for (int p = 0; p < 2; p++) {
            int idx = tid + p * 256;
            int srow = idx >> 2, skc = (idx & 3) * 8;
            int gr = min(m0 + srow, M - 1);
            *(uint4*)(&sAh[srow * 40 + skc]) = *(const uint4*)(Ah + (size_t)gr * K + kk + skc);
            *(uint4*)(&sAl[srow * 40 + skc]) = *(const uint4*)(Al + (size_t)gr * K + kk + skc);
            int gn = n0 + srow;
            *(uint4*)(&sBh[srow * 40 + skc]) = *(const uint4*)(BTh + (size_t)gn * K + kk + skc);
            *(uint4*)(&sBl[srow * 40 + skc]) = *(const uint4*)(BTl + (size_t)gn * K + kk + skc);
        }
        __syncthreads();

        short8 ah[4], al[4];
        #pragma unroll
        for (int i = 0; i < 4; i++) {
            int arow = wr + i * 16 + l15;
            ah[i] = *(const short8*)(&sAh[arow * 40 + l4 * 8]);
            al[i] = *(const short8*)(&sAl[arow * 40 + l4 * 8]);
        }
        #pragma unroll
        for (int j = 0; j < 4; j++) {
            int bcol = wc + j * 16 + l15;
            short8 bh = *(const short8*)(&sBh[bcol * 40 + l4 * 8]);
            short8 bl = *(const short8*)(&sBl[bcol * 40 + l4 * 8]);
            #pragma unroll
            for (int i = 0; i < 4; i++) {
                acc[i][j] = __builtin_amdgcn_mfma_f32_16x16x32_bf16(ah[i], bh, acc[i][j], 0, 0, 0);
                acc[i][j] = __builtin_amdgcn_mfma_f32_16x16x32_bf16(al[i], bh, acc[i][j], 0, 0, 0);
                acc[i][j] = __builtin_amdgcn_mfma_f32_16x16x32_bf16(ah[i], bl, acc[i][j], 0, 0, 0);
            }
        }
    }

    const int fp32 = flag[1];
    #pragma unroll
    for (int j = 0; j < 4; j++) {
        int col = n0 + wc + j * 16 + l15;
        float bv = inval(biasraw, fp32, col);
        #pragma unroll
        for (int i = 0; i < 4; i++) {
            #pragma unroll
            for (int r = 0; r < 4; r++) {
                int row = m0 + wr + i * 16 + l4 * 4 + r;
                if (row < M) {
                    float v = acc[i][j][r] + bv;
                    v = v > 0.f ? v : 0.1f * v;
                    u16 hi = f2bf(v);
                    Ch[(size_t)row * N + col] = hi;
                    Cl[(size_t)row * N + col] = f2bf(v - bf2f(hi));
                }
            }
        }
    }
}

// ---------------------------------------------------------------------------
// GATv2: wave-per-node, online softmax; edge loop unrolled x2;
// wave-uniform conditional rescale (rescale only when the running max changes).
// ---------------------------------------------------------------------------
__global__ __launch_bounds__(256)
void gat_wave_kernel(const int* __restrict__ rowptr, const int* __restrict__ esrcp,
                     const float* __restrict__ xl, const float* __restrict__ xr,
                     const void* __restrict__ att, const void* __restrict__ bias,
                     const int* __restrict__ flag,
                     u16* __restrict__ hh, u16* __restrict__ hl)
{
    int lane = threadIdx.x & 63, wv = threadIdx.x >> 6;
    int n = blockIdx.x * 4 + wv;
    if (n >= N_NODES) return;
    int fp32 = flag[1];
    int d0 = lane * 8;

    const float* xrr = xr + (size_t)n * D_EMB;
    float4 r0 = *(const float4*)(xrr + d0);
    float4 r1 = *(const float4*)(xrr + d0 + 4);
    float xrv[8] = {r0.x, r0.y, r0.z, r0.w, r1.x, r1.y, r1.z, r1.w};
    float attv[8];
    #pragma unroll
    for (int k = 0; k < 8; k++) attv[k] = inval(att, fp32, d0 + k);

    int beg = rowptr[n], end = rowptr[n + 1];
    float m_run = -3.4e38f, s_run = 0.f;
    float acc[8] = {0.f, 0.f, 0.f, 0.f, 0.f, 0.f, 0.f, 0.f};

    int j = beg;
    for (; j + 2 <= end; j += 2) {
        int s0 = esrcp[j], s1 = esrcp[j + 1];
        const float* x0 = xl + (size_t)s0 * D_EMB;
        const float* x1 = xl + (size_t)s1 * D_EMB;
        float4 p0 = *(const float4*)(x0 + d0);
        float4 p1 = *(const float4*)(x0 + d0 + 4);
        float4 q0 = *(const float4*)(x1 + d0);
        float4 q1 = *(const float4*)(x1 + d0 + 4);
        float v0[8] = {p0.x, p0.y, p0.z, p0.w, p1.x, p1.y, p1.z, p1.w};
        float v1[8] = {q0.x, q0.y, q0.z, q0.w, q1.x, q1.y, q1.z, q1.w};
        float e0 = 0.f, e1 = 0.f;
        #pragma unroll
        for (int k = 0; k < 8; k++) {
            float t = v0[k] + xrv[k]; t = t > 0.f ? t : 0.2f * t; e0 += attv[k] * t;
            float u = v1[k] + xrv[k]; u = u > 0.f ? u : 0.2f * u; e1 += attv[k] * u;
        }
        #pragma unroll
        for (int o = 32; o > 0; o >>= 1) {
            e0 += __shfl_xor(e0, o);
            e1 += __shfl_xor(e1, o);
        }
        // e0/e1 are lane-uniform -> uniform branches
        if (e0 > m_run) {
            float sc = __expf(m_run - e0);
            s_run = s_run * sc + 1.f;
            #pragma unroll
            for (int k = 0; k < 8; k++) acc[k] = acc[k] * sc + v0[k];
            m_run = e0;
        } else {
            float w = __expf(e0 - m_run);
            s_run += w;
            #pragma unroll
            for (int k = 0; k < 8; k++) acc[k] += w * v0[k];
        }
        if (e1 > m_run) {
            float sc = __expf(m_run - e1);
            s_run = s_run * sc + 1.f;
            #pragma unroll
            for (int k = 0; k < 8; k++) acc[k] = acc[k] * sc + v1[k];
            m_run = e1;
        } else {
            float w = __expf(e1 - m_run);
            s_run += w;
            #pragma unroll
            for (int k = 0; k < 8; k++) acc[k] += w * v1[k];
        }
    }
    if (j < end) {
        int s0 = esrcp[j];
        const float* x0 = xl + (size_t)s0 * D_EMB;
        float4 p0 = *(const float4*)(x0 + d0);
        float4 p1 = *(const float4*)(x0 + d0 + 4);
        float v0[8] = {p0.x, p0.y, p0.z, p0.w, p1.x, p1.y, p1.z, p1.w};
        float e0 = 0.f;
        #pragma unroll
        for (int k = 0; k < 8; k++) {
            float t = v0[k] + xrv[k]; t = t > 0.f ? t : 0.2f * t; e0 += attv[k] * t;
        }
        #pragma unroll
        for (int o = 32; o > 0; o >>= 1) e0 += __shfl_xor(e0, o);
        if (e0 > m_run) {
            float sc = __expf(m_run - e0);
            s_run = s_run * sc + 1.f;
            #pragma unroll
            for (int k = 0; k < 8; k++) acc[k] = acc[k] * sc + v0[k];
            m_run = e0;
        } else {
            float w = __expf(e0 - m_run);
            s_run += w;
            #pragma unroll
            for (int k = 0; k < 8; k++) acc[k] += w * v0[k];
        }
    }

    float inv = 1.f / (s_run + 1e-16f);
    union { uint4 q; u16 us[8]; } ph, pl;
    #pragma unroll
    for (int k = 0; k < 8; k++) {
        float h = tanhf(acc[k] * inv + inval(bias, fp32, d0 + k));
        u16 hi = f2bf(h);
        ph.us[k] = hi;
        pl.us[k] = f2bf(h - bf2f(hi));
    }
    *(uint4*)(&hh[(size_t)n * D_EMB + d0]) = ph.q;
    *(uint4*)(&hl[(size_t)n * D_EMB + d0]) = pl.q;
}

// ---------------------------------------------------------------------------
__global__ __launch_bounds__(256)
void logit_kernel(const u16* __restrict__ m2h, const u16* __restrict__ m2l,
                  const void* __restrict__ A3, const void* __restrict__ c3,
                  const int* __restrict__ flag,
                  float* __restrict__ logits)
{
    int tid = threadIdx.x, lane = tid & 63, wv = tid >> 6;
    int node = blockIdx.x * 4 + wv;
    if (node >= N_NODES) return;
    int fp32 = flag[1];
    const u16* rh = m2h + (size_t)node * D_HID;
    const u16* rl = m2l + (size_t)node * D_HID;
    int d0 = lane * 4;
    float a = 0.f;
    #pragma unroll
    for (int j = 0; j < 4; j++) {
        float hv = bf2f(rh[d0 + j]) + bf2f(rl[d0 + j]);
        a += hv * inval(A3, fp32, d0 + j);
    }
    #pragma unroll
    for (int o = 32; o > 0; o >>= 1) a += __shfl_down(a, o);
    if (lane == 0) logits[node] = a + inval(c3, fp32, 0);
}

// ---------------------------------------------------------------------------
__global__ __launch_bounds__(256)
void softmax_kernel(const float* __restrict__ logits, float* __restrict__ out)
{
    __shared__ float red[4];
    __shared__ float s_m, s_s;
    int tid = threadIdx.x, lane = tid & 63, wv = tid >> 6;
    float m = -3.4e38f;
    for (int i = tid; i < N_NODES; i += 256) m = fmaxf(m, logits[i]);
    #pragma unroll
    for (int o = 32; o > 0; o >>= 1) m = fmaxf(m, __shfl_down(m, o));
    if (lane == 0) red[wv] = m;
    __syncthreads();
    if (tid == 0) {
        float mm = red[0];
        for (int i = 1; i < 4; i++) mm = fmaxf(mm, red[i]);
        s_m = mm;
    }
    __syncthreads();
    float mm = s_m;
    float s = 0.f;
    for (int i = tid; i < N_NODES; i += 256) s += __expf(logits[i] - mm);
    #pragma unroll
    for (int o = 32; o > 0; o >>= 1) s += __shfl_down(s, o);
    if (lane == 0) red[wv] = s;
    __syncthreads();
    if (tid == 0) {
        float ss = 0.f;
        for (int i = 0; i < 4; i++) ss += red[i];
        s_s = ss;
    }
    __syncthreads();
    float invs = 1.f / s_s;
    for (int i = tid; i < N_NODES; i += 256) out[i] = __expf(logits[i] - mm) * invs;
}

// ---------------------------------------------------------------------------
extern "C" void kernel_launch(void* const* d_in, const int* in_sizes, int n_in,
                              void* d_out, int out_size, void* d_ws, size_t ws_size,
                              hipStream_t stream)
{
    const void* x   = d_in[0];
    const int*  ei  = (const int*)d_in[1];
    const void* Wl[3]  = {d_in[2],  d_in[6],  d_in[10]};
    const void* Wr[3]  = {d_in[3],  d_in[7],  d_in[11]};
    const void* att[3] = {d_in[4],  d_in[8],  d_in[12]};
    const void* bia[3] = {d_in[5],  d_in[9],  d_in[13]};
    const void* A1 = d_in[14];
    const void* c1 = d_in[15];
    const void* A2 = d_in[16];
    const void* c2 = d_in[17];
    const void* A3 = d_in[18];
    const void* c3 = d_in[19];

    char* p = (char*)d_ws;
    auto alloc = [&](size_t bytes) {
        char* r = p;
        p += (bytes + 255) & ~(size_t)255;
        return r;
    };
    float* xl     = (float*)alloc((size_t)N_NODES * D_EMB * 4);
    float* xr     = (float*)alloc((size_t)N_NODES * D_EMB * 4);
    u16*   hh     = (u16*)  alloc((size_t)N_NODES * D_EMB * 2);
    u16*   hl     = (u16*)  alloc((size_t)N_NODES * D_EMB * 2);
    int*   esrcp  = (int*)  alloc((size_t)N_EDGES * 4);
    int*   rowptr = (int*)  alloc((size_t)(N_NODES + 1) * 4);
    int*   counts = (int*)  alloc((size_t)N_NODES * 4);
    int*   flag   = (int*)  alloc(256);
    u16* wl1h = (u16*)alloc(D_EMB * D_IN  * 2); u16* wl1l = (u16*)alloc(D_EMB * D_IN  * 2);
    u16* wr1h = (u16*)alloc(D_EMB * D_IN  * 2); u16* wr1l = (u16*)alloc(D_EMB * D_IN  * 2);
    u16* wl2h = (u16*)alloc(D_EMB * D_EMB * 2); u16* wl2l = (u16*)alloc(D_EMB * D_EMB * 2);
    u16* wr2h = (u16*)alloc(D_EMB * D_EMB * 2); u16* wr2l = (u16*)alloc(D_EMB * D_EMB * 2);
    u16* wl3h = (u16*)alloc(D_EMB * D_EMB * 2); u16* wl3l = (u16*)alloc(D_EMB * D_EMB * 2);
    u16* wr3h = (u16*)alloc(D_EMB * D_EMB * 2); u16* wr3l = (u16*)alloc(D_EMB * D_EMB * 2);
    u16* a1h  = (u16*)alloc(D_EMB * D_HID * 2); u16* a1l  = (u16*)alloc(D_EMB * D_HID * 2);
    u16* a2h  = (u16*)alloc(D_HID * D_HID * 2); u16* a2l  = (u16*)alloc(D_HID * D_HID * 2);
    size_t needed = (size_t)(p - (char*)d_ws);

    if (ws_size < needed) {
        sentinel_kernel<<<(out_size + 255) / 256, 256, 0, stream>>>((float*)d_out, out_size);
        return;
    }

    u16* xph = hh;                         // x pair aliases hh/hl (dead until gat1)
    u16* xpl = hl;
    u16* m1h = (u16*)xl;
    u16* m1l = (u16*)((char*)xl + 5120000);
    u16* m2h = (u16*)((char*)xl + 10240000);
    u16* m2l = (u16*)((char*)xl + 15360000);
    float* logits = (float*)xr;

    detect_kernel<<<1, 256, 0, stream>>>(ei, (const u16*)x, flag);

    // CSR
    zero_counts_kernel<<<(N_NODES + 255) / 256, 256, 0, stream>>>(counts);
    count_edges_kernel<<<(N_EDGES + 255) / 256, 256, 0, stream>>>(ei, flag, counts);
    scan_counts_kernel<<<1, 256, 0, stream>>>(counts, rowptr);
    fill_esrcp_kernel<<<(N_EDGES + 255) / 256, 256, 0, stream>>>(ei, flag, counts, esrcp);

    // fused preconversion (9 jobs, 1 dispatch)
    ConvJobs jobs;
    auto setjob = [&](int i, const void* s, u16* dh, u16* dl, int r, int c, int tr) {
        jobs.src[i] = s; jobs.dh[i] = dh; jobs.dl[i] = dl;
        jobs.rows[i] = r; jobs.cols[i] = c; jobs.trans[i] = tr;
    };
    setjob(0, x,     xph,  xpl,  N_NODES, D_IN, 0);
    setjob(1, Wl[0], wl1h, wl1l, D_IN,  D_EMB, 1);
    setjob(2, Wr[0], wr1h, wr1l, D_IN,  D_EMB, 1);
    setjob(3, Wl[1], wl2h, wl2l, D_EMB, D_EMB, 1);
    setjob(4, Wr[1], wr2h, wr2l, D_EMB, D_EMB, 1);
    setjob(5, Wl[2], wl3h, wl3l, D_EMB, D_EMB, 1);
    setjob(6, Wr[2], wr3h, wr3l, D_EMB, D_EMB, 1);
    setjob(7, A1,    a1h,  a1l,  D_EMB, D_HID, 1);
    setjob(8, A2,    a2h,  a2l,  D_HID, D_HID, 1);
    jobs.njobs = 9;
    jobs.cum[0] = 0;
    for (int i = 0; i < 9; i++) jobs.cum[i + 1] = jobs.cum[i] + jobs.rows[i] * jobs.cols[i];
    int ctotal = jobs.cum[9];
    convert_fused_kernel<<<(ctotal + 255) / 256, 256, 0, stream>>>(jobs, flag);

    dim3 gdual(2 * D_EMB / 128, (N_NODES + 127) / 128);   // (8, 79)
    dim3 gmlp1(D_HID / 128, (N_NODES + 127) / 128);       // (2, 79)
    int gatgrid = (N_NODES + 3) / 4;

    // layer 1
    gemm_dual_kernel<<<gdual, 256, 0, stream>>>(xph, xpl, wl1h, wl1l, wr1h, wr1l, xl, xr, N_NODES, D_EMB, D_IN);
    gat_wave_kernel<<<gatgrid, 256, 0, stream>>>(rowptr, esrcp, xl, xr, att[0], bia[0], flag, hh, hl);
    // layer 2
    gemm_dual_kernel<<<gdual, 256, 0, stream>>>(hh, hl, wl2h, wl2l, wr2h, wr2l, xl, xr, N_NODES, D_EMB, D_EMB);
    gat_wave_kernel<<<gatgrid, 256, 0, stream>>>(rowptr, esrcp, xl, xr, att[1], bia[1], flag, hh, hl);
    // layer 3
    gemm_dual_kernel<<<gdual, 256, 0, stream>>>(hh, hl, wl3h, wl3l, wr3h, wr3l, xl, xr, N_NODES, D_EMB, D_EMB);
    gat_wave_kernel<<<gatgrid, 256, 0, stream>>>(rowptr, esrcp, xl, xr, att[2], bia[2], flag, hh, hl);

    // MLP
    gemm_pair_kernel<<<gmlp1, 256, 0, stream>>>(hh, hl, a1h, a1l, m1h, m1l, c1, flag, N_NODES, D_HID, D_EMB);
    gemm_pair_kernel<<<gmlp1, 256, 0, stream>>>(m1h, m1l, a2h, a2l, m2h, m2l, c2, flag, N_NODES, D_HID, D_HID);
    logit_kernel<<<(N_NODES + 3) / 4, 256, 0, stream>>>(m2h, m2l, A3, c3, flag, logits);
    softmax_kernel<<<1, 256, 0, stream>>>(logits, (float*)d_out);
}